// Round 3
// baseline (310.326 us; speedup 1.0000x reference)
//
#include <hip/hip_runtime.h>

#define SEQ     2048
#define HDIM    1024
#define TOKENS  4096   // B*SEQ
#define NHEADS  16
#define HS      64
#define LP      72     // padded LDS row stride (elements): 144B, 16B-aligned

typedef __bf16 v8bf __attribute__((ext_vector_type(8)));
typedef float  v4f  __attribute__((ext_vector_type(4)));

#define MFMA16(a, b, c) __builtin_amdgcn_mfma_f32_16x16x32_bf16((a), (b), (c), 0, 0, 0)

// scores arrive in log2 units: 1/sqrt(64) * log2(e) folded into Q pre-scale
#define QSCALE (0.125f * 1.44269504088896f)

__device__ __forceinline__ unsigned short f2bf(float f) {
  unsigned int u = __float_as_uint(f);
  u += 0x7FFFu + ((u >> 16) & 1u);   // RNE
  return (unsigned short)(u >> 16);
}

__device__ __forceinline__ void async16(const void* g, void* l) {
  __builtin_amdgcn_global_load_lds(
      (const __attribute__((address_space(1))) void*)g,
      (__attribute__((address_space(3))) void*)l, 16, 0, 0);
}

// ---------------- fused prep: x casts + both weight transposes ----------------
__global__ __launch_bounds__(256) void prep_all_kernel(
    const float* __restrict__ x, const float* __restrict__ pos,
    const float* __restrict__ Wqkv, const float* __restrict__ Wout,
    unsigned short* __restrict__ X, unsigned short* __restrict__ XP,
    unsigned short* __restrict__ WQT, unsigned short* __restrict__ WOT) {
  __shared__ float tile[32][33];
  const int id = blockIdx.x;
  if (id < 4096) {
    const int i = (id * 256 + threadIdx.x) * 4;
    float4 xv = *(const float4*)(x + i);
    float4 pv = *(const float4*)(pos + (i & (SEQ * HDIM - 1)));
    ushort4 a, b;
    a.x = f2bf(xv.x); a.y = f2bf(xv.y); a.z = f2bf(xv.z); a.w = f2bf(xv.w);
    b.x = f2bf(xv.x + pv.x); b.y = f2bf(xv.y + pv.y);
    b.z = f2bf(xv.z + pv.z); b.w = f2bf(xv.w + pv.w);
    *(ushort4*)(X + i) = a;
    *(ushort4*)(XP + i) = b;
    return;
  }
  const float* in; unsigned short* out; int R, C, bx, by;
  if (id < 7168) {
    const int t2 = id - 4096;
    in = Wqkv; out = WQT; R = HDIM; C = 3 * HDIM;
    bx = (t2 % 96) * 32; by = (t2 / 96) * 32;
  } else {
    const int t3 = id - 7168;
    in = Wout; out = WOT; R = HDIM; C = HDIM;
    bx = (t3 & 31) * 32; by = (t3 >> 5) * 32;
  }
  const int tx = threadIdx.x & 31, ty = threadIdx.x >> 5;  // (32,8)
#pragma unroll
  for (int j = 0; j < 32; j += 8)
    tile[ty + j][tx] = in[(size_t)(by + ty + j) * C + bx + tx];
  __syncthreads();
#pragma unroll
  for (int j = 0; j < 32; j += 8)
    out[(size_t)(bx + ty + j) * R + by + tx] = f2bf(tile[tx][ty + j]);
}

// ---------------- GEMM1: C(4096x3072) = Aeff(4096x1024) @ Wt(3072x1024)^T ----------------
// R0 serial 2-barrier structure (proven best: explicit vmcnt pipelines regressed
// in R1/R2, matching guide m131-m141 nulls). Change vs R0: 512-thread blocks,
// same 128x128 tile -> 8 waves/block x 3 blocks/CU = 6 waves/SIMD (was 3).
// The K-step drain (~400-500cy) needs ~3 extra waves of MFMA work to hide;
// 3 waves/SIMD couldn't, 6 can. Per-wave tile 64x32, acc 4x2 (32 VGPR);
// __launch_bounds__(512,6) caps VGPR at 85 to guarantee 3-block residency.
// V blocks compute C^T via operand swap so the V^T store is 32B s-runs.
__global__ __launch_bounds__(512, 6) void gemm_qkv_kernel(
    const unsigned short* __restrict__ XP, const unsigned short* __restrict__ X,
    const unsigned short* __restrict__ Wt,
    unsigned short* __restrict__ Qb, unsigned short* __restrict__ Kb,
    unsigned short* __restrict__ VTb) {
  __shared__ unsigned short As[2][128 * 32];
  __shared__ unsigned short Bs[2][128 * 32];
  const int m0 = blockIdx.x * 128;
  const int n0 = blockIdx.y * 128;
  const bool isV = (n0 >= 2 * HDIM);
  const unsigned short* A = isV ? X : XP;
  const int t = threadIdx.x;
  const int lane = t & 63, w = t >> 6;             // w: 0..7
  const int wm = (w >> 2) * 64, wn = (w & 3) * 32; // wave tile 64x32
  const int quad = lane >> 4, l15 = lane & 15;

  v4f acc[4][2] = {};

  const int rowA = t >> 2;          // 0..127
  const int colA = (t & 3) * 8;     // 0..24
  const unsigned short* gA = A + (size_t)(m0 + rowA) * HDIM + colA;
  const unsigned short* gB = Wt + (size_t)(n0 + rowA) * HDIM + colA;

  for (int k0 = 0; k0 < HDIM; k0 += 64) {
    __syncthreads();
#pragma unroll
    for (int kh = 0; kh < 2; kh++) {
      async16(gA + k0 + kh * 32, &As[kh][t * 8]);
      async16(gB + k0 + kh * 32, &Bs[kh][t * 8]);
    }
    __syncthreads();
#pragma unroll
    for (int kh = 0; kh < 2; kh++) {
      v8bf a[4], b[2];
#pragma unroll
      for (int i = 0; i < 4; i++)
        a[i] = *(const v8bf*)&As[kh][(wm + i * 16 + l15) * 32 + quad * 8];
#pragma unroll
      for (int j = 0; j < 2; j++)
        b[j] = *(const v8bf*)&Bs[kh][(wn + j * 16 + l15) * 32 + quad * 8];
      if (isV) {
#pragma unroll
        for (int i = 0; i < 4; i++)
#pragma unroll
          for (int j = 0; j < 2; j++)
            acc[i][j] = MFMA16(b[j], a[i], acc[i][j]);   // C^T
      } else {
#pragma unroll
        for (int i = 0; i < 4; i++)
#pragma unroll
          for (int j = 0; j < 2; j++)
            acc[i][j] = MFMA16(a[i], b[j], acc[i][j]);
      }
    }
  }

  const int b_ = m0 >> 11;
  const int s0 = m0 & (SEQ - 1);

  if (isV) {
    // acc[i][j] = C^T: D[row=quad*4+r -> Wt col (d)][col=l15 -> token (s)]
#pragma unroll
    for (int i = 0; i < 4; i++) {
#pragma unroll
      for (int j = 0; j < 2; j++) {
        const int s_ = s0 + wm + i * 16 + l15;
#pragma unroll
        for (int r = 0; r < 4; r++) {
          const int c2 = (n0 - 2 * HDIM) + wn + j * 16 + quad * 4 + r;
          const int h = c2 >> 6, d = c2 & 63;
          VTb[((size_t)(((b_ << 4) | h) * HS + d)) * SEQ + s_] = f2bf(acc[i][j][r]);
        }
      }
    }
  } else {
    // Q/K[(b,h,s), d]: scatter, 16 consecutive lanes form 32B d-runs
    const float scale = (n0 < HDIM) ? QSCALE : 1.0f;
    unsigned short* dst = (n0 < HDIM) ? Qb : Kb;
#pragma unroll
    for (int i = 0; i < 4; i++) {
#pragma unroll
      for (int j = 0; j < 2; j++) {
#pragma unroll
        for (int r = 0; r < 4; r++) {
          const int s_ = s0 + wm + i * 16 + quad * 4 + r;
          const int c2 = (n0 & (HDIM - 1)) + wn + j * 16 + l15;
          const int h = c2 >> 6, d = c2 & 63;
          dst[((size_t)(((b_ << 4) | h) * SEQ + s_)) * HS + d] =
              f2bf(acc[i][j][r] * scale);
        }
      }
    }
  }
}

// ---------------- flash attention, complementary-pair balanced + Qs/Ps union --------
// Block (bh, p): q-tiles qlo=p and qhi=31-p (64 rows each), one K/V stream over
// chunks 0..qhi; exactly 33 chunk-tiles per block. Qs (dead after fragment
// load) is overlaid by per-wave Ps => LDS 36,864 B => 4 blocks/CU at 88 VGPR.
// NOTE: launch_bounds min-waves MUST stay 2 — forcing 4 caps VGPR at 64 and
// spills ~60MB to scratch (R10: dur 46->109us, WRITE 8->68MB).
__global__ __launch_bounds__(256, 2) void attn_pair_kernel(
    const unsigned short* __restrict__ Qp, const unsigned short* __restrict__ Kp,
    const unsigned short* __restrict__ Vp, unsigned short* __restrict__ ATTN) {
  __shared__ unsigned short SM[18432];       // 36,864 B
  unsigned short* Ks = SM;                   // 64*LP
  unsigned short* Vs = SM + 4608;            // 64*LP (V^T chunk: [d][key])
  unsigned short* QPs = SM + 9216;           // 128*LP union: Qs (init) / Ps (loop)

  const int bh = blockIdx.x;
  const int p  = blockIdx.y;        // 0..15
  const int b_ = bh >> 4, h = bh & 15;
  const int qlo = p, qhi = 31 - p;
  const int q0lo = qlo * 64, q0hi = qhi * 64;
  const int t = threadIdx.x;
  const int lane = t & 63, w = t >> 6;
  const int quad = lane >> 4, l15 = lane & 15;

  const unsigned short* Qg = Qp + (size_t)bh * SEQ * HS;
  const unsigned short* Kg = Kp + (size_t)bh * SEQ * HS;
  const unsigned short* Vg = Vp + (size_t)bh * HS * SEQ;

  const int sr = t >> 3, scol = (t & 7) * 8;
  *(uint4*)&QPs[sr * LP + scol] = *(const uint4*)(Qg + (size_t)(q0lo + sr) * HS + scol);
  *(uint4*)&QPs[(sr + 32) * LP + scol] =
      *(const uint4*)(Qg + (size_t)(q0lo + sr + 32) * HS + scol);
  *(uint4*)&QPs[(sr + 64) * LP + scol] =
      *(const uint4*)(Qg + (size_t)(q0hi + sr) * HS + scol);
  *(uint4*)&QPs[(sr + 96) * LP + scol] =
      *(const uint4*)(Qg + (size_t)(q0hi + sr + 32) * HS + scol);
  __syncthreads();

  // Q rows as B-operand fragments: [tile][khalf]. After these ds_reads drain
  // (at the first in-loop __syncthreads), QPs is reused as per-wave Ps.
  v8bf bq[2][2];
#pragma unroll
  for (int tl = 0; tl < 2; tl++)
#pragma unroll
    for (int kh = 0; kh < 2; kh++)
      bq[tl][kh] = *(const v8bf*)&QPs[(tl * 64 + w * 16 + l15) * LP + kh * 32 + quad * 8];

  unsigned short* Ps_w = QPs + w * 32 * LP;  // 32 rows/wave: 0-15 lo, 16-31 hi

  v8bf ones;
#pragma unroll
  for (int j = 0; j < 8; j++) ones[j] = (__bf16)1.0f;

  v4f o[2][4] = {};
  v4f lacc[2] = {};

  // register prefetch of chunk 0
  uint4 kr0, kr1, vr0, vr1;
  kr0 = *(const uint4*)(Kg + (size_t)sr * HS + scol);
  kr1 = *(const uint4*)(Kg + (size_t)(sr + 32) * HS + scol);
  vr0 = *(const uint4*)(Vg + (size_t)sr * SEQ + scol);
  vr1 = *(const uint4*)(Vg + (size_t)(sr + 32) * SEQ + scol);

  const int qrow_hi = q0hi + w * 16 + l15;  // lane's q-row in S^T
  const int qrow_lo = q0lo + w * 16 + l15;

  for (int cI = 0; cI <= qhi; cI++) {
    const int kc = cI * 64;
    __syncthreads();  // previous chunk's K/V (and init bq) LDS reads done
    *(uint4*)&Ks[sr * LP + scol] = kr0;
    *(uint4*)&Ks[(sr + 32) * LP + scol] = kr1;
    *(uint4*)&Vs[sr * LP + scol] = vr0;
    *(uint4*)&Vs[(sr + 32) * LP + scol] = vr1;
    if (cI < qhi) {  // prefetch next chunk while computing this one
      const int kn = kc + 64;
      kr0 = *(const uint4*)(Kg + (size_t)(kn + sr) * HS + scol);
      kr1 = *(const uint4*)(Kg + (size_t)(kn + sr + 32) * HS + scol);
      vr0 = *(const uint4*)(Vg + (size_t)sr * SEQ + kn + scol);
      vr1 = *(const uint4*)(Vg + (size_t)(sr + 32) * SEQ + kn + scol);
    }
    __syncthreads();

    // K fragments (A-operand), shared across both tiles
    v8bf kf0[4], kf1[4];
#pragma unroll
    for (int ni = 0; ni < 4; ni++) {
      kf0[ni] = *(const v8bf*)&Ks[(ni * 16 + l15) * LP + quad * 8];
      kf1[ni] = *(const v8bf*)&Ks[(ni * 16 + l15) * LP + 32 + quad * 8];
    }

    const bool doLo = (cI <= qlo);

    // ---- hi tile: S^T = K Q^T, D[key=quad*4+r][qrow=l15] ----
    {
      v4f sc[4] = {};
#pragma unroll
      for (int ni = 0; ni < 4; ni++) {
        sc[ni] = MFMA16(kf0[ni], bq[1][0], sc[ni]);
        sc[ni] = MFMA16(kf1[ni], bq[1][1], sc[ni]);
      }
      if (cI == qhi) {
#pragma unroll
        for (int ni = 0; ni < 4; ni++) {
          const int key = kc + ni * 16 + quad * 4;
#pragma unroll
          for (int r = 0; r < 4; r++)
            if (key + r > qrow_hi) sc[ni][r] = -1e30f;
        }
      }
#pragma unroll
      for (int ni = 0; ni < 4; ni++) {
        const float p0 = exp2f(sc[ni][0]), p1 = exp2f(sc[ni][1]);
        const float p2 = exp2f(sc[ni][2]), p3 = exp2f(sc[ni][3]);
        uint2 pk;
        pk.x = __builtin_amdgcn_perm(__float_as_uint(p1), __float_as_uint(p0), 0x07060302u);
        pk.y = __builtin_amdgcn_perm(__float_as_uint(p3), __float_as_uint(p2), 0x07060302u);
        *(uint2*)&Ps_w[(16 + l15) * LP + ni * 16 + quad * 4] = pk;
      }
    }
    // ---- lo tile (wave-uniform skip once cI > qlo) ----
    if (doLo) {
      v4f sc[4] = {};
#pragma unroll
      for (int ni = 0; ni < 4; ni++) {
        sc[ni] = MFMA16(kf0[ni], bq[0][0], sc[ni]);
        sc[ni] = MFMA16(kf1[ni], bq[0][1], sc[ni]);
      }
      if (cI == qlo) {
#pragma unroll
        for (int ni = 0; ni < 4; ni++) {
          const int key = kc + ni * 16 + quad * 4;
#pragma unroll
          for (int r = 0; r < 4; r++)
            if (key + r > qrow_lo) sc[ni][r] = -1e30f;
        }
      }
#pragma unroll
      for (int ni = 0; ni < 4; ni++) {
        const float p0 = exp2f(sc[ni][0]), p1 = exp2f(sc[ni][1]);
        const float p2 = exp2f(sc[ni][2]), p3 = exp2f(sc[ni][3]);
        uint2 pk;
        pk.x = __builtin_amdgcn_perm(__float_as_uint(p1), __float_as_uint(p0), 0x07060302u);
        pk.y = __builtin_amdgcn_perm(__float_as_uint(p3), __float_as_uint(p2), 0x07060302u);
        *(uint2*)&Ps_w[l15 * LP + ni * 16 + quad * 4] = pk;
      }
    }

    // ---- O += P @ V, l += P @ 1; V fragments shared across tiles ----
#pragma unroll
    for (int ki = 0; ki < 2; ki++) {
      v8bf pahi = *(const v8bf*)&Ps_w[(16 + l15) * LP + ki * 32 + quad * 8];
      lacc[1] = MFMA16(pahi, ones, lacc[1]);
      v8bf palo;
      if (doLo) {
        palo = *(const v8bf*)&Ps_w[l15 * LP + ki * 32 + quad * 8];
        lacc[0] = MFMA16(palo, ones, lacc[0]);
      }
#pragma unroll
      for (int ni = 0; ni < 4; ni++) {
        v8bf vb = *(const v8bf*)&Vs[(ni * 16 + l15) * LP + ki * 32 + quad * 8];
        o[1][ni] = MFMA16(pahi, vb, o[1][ni]);
        if (doLo) o[0][ni] = MFMA16(palo, vb, o[0][ni]);
      }
    }
  }

  // epilogue: normalize and store both tiles (C-layout rows = quad*4+r)
#pragma unroll
  for (int tl = 0; tl < 2; tl++) {
    const int q0 = tl ? q0hi : q0lo;
    const int row_base = q0 + w * 16 + quad * 4;
    float invl[4];
#pragma unroll
    for (int r = 0; r < 4; r++) invl[r] = 1.0f / lacc[tl][r];
#pragma unroll
    for (int ni = 0; ni < 4; ni++)
#pragma unroll
      for (int r = 0; r < 4; r++) {
        const int tr = b_ * SEQ + row_base + r;
        ATTN[(size_t)tr * HDIM + h * HS + ni * 16 + l15] = f2bf(o[tl][ni][r] * invl[r]);
      }
  }
}

// ---------------- GEMM2: out(4096x1024) = ATTN @ WOT^T, fp32 out ----------------
// 128x64 tiles -> 512 blocks (2/CU); 3-deep counted-vmcnt pipeline (KEPT from
// R1/R2: at 2 blocks/CU there is no inter-block overlap, so the explicit
// pipeline is what hides load latency here — R1 gained ~8-12us on this kernel).
__global__ __launch_bounds__(256) void gemm_out_kernel(
    const unsigned short* __restrict__ Ab, const unsigned short* __restrict__ Wt,
    float* __restrict__ out) {
  __shared__ unsigned short As[3][128 * 32];
  __shared__ unsigned short Bs[3][64 * 32];
  const int m0 = blockIdx.x * 128;
  const int n0 = blockIdx.y * 64;
  const int t = threadIdx.x;
  const int lane = t & 63, w = t >> 6;
  const int wm = w * 32;
  const int quad = lane >> 4, l15 = lane & 15;

  v4f acc[2][4] = {};

  const int rowA = t >> 2;
  const int colA = (t & 3) * 8;
  const unsigned short* gA = Ab + (size_t)(m0 + rowA) * HDIM + colA;
  const unsigned short* gB = Wt + (size_t)(n0 + rowA) * HDIM + colA;

  auto issue = [&](int k0, int buf) {
    async16(gA + k0, &As[buf][t * 8]);
    async16(gA + 64 * HDIM + k0, &As[buf][2048 + t * 8]);
    async16(gB + k0, &Bs[buf][t * 8]);   // rowA is always <64: all threads load B
  };
  auto compute = [&](int buf) {
    v8bf a[2], b[4];
#pragma unroll
    for (int i = 0; i < 2; i++)
      a[i] = *(const v8bf*)&As[buf][(wm + i * 16 + l15) * 32 + quad * 8];
#pragma unroll
    for (int j = 0; j < 4; j++)
      b[j] = *(const v8bf*)&Bs[buf][(j * 16 + l15) * 32 + quad * 8];
#pragma unroll
    for (int i = 0; i < 2; i++)
#pragma unroll
      for (int j = 0; j < 4; j++)
        acc[i][j] = MFMA16(a[i], b[j], acc[i][j]);
  };

  issue(0, 0);
  issue(32, 1);
  asm volatile("s_waitcnt vmcnt(3)" ::: "memory");
  __builtin_amdgcn_s_barrier();
  asm volatile("" ::: "memory");

  int cur = 0;
#pragma unroll 3
  for (int kt = 0; kt < 30; ++kt) {
    int ib = cur + 2; if (ib >= 3) ib -= 3;
    issue((kt + 2) * 32, ib);
    compute(cur);
    asm volatile("s_waitcnt vmcnt(3)" ::: "memory");
    __builtin_amdgcn_s_barrier();
    asm volatile("" ::: "memory");
    if (++cur == 3) cur = 0;
  }
  compute(cur);
  asm volatile("s_waitcnt vmcnt(0)" ::: "memory");
  __builtin_amdgcn_s_barrier();
  asm volatile("" ::: "memory");
  if (++cur == 3) cur = 0;
  compute(cur);

#pragma unroll
  for (int i = 0; i < 2; i++) {
#pragma unroll
    for (int j = 0; j < 4; j++) {
#pragma unroll
      for (int r = 0; r < 4; r++) {
        const int tr = m0 + wm + i * 16 + quad * 4 + r;
        const int c = n0 + j * 16 + l15;
        out[(size_t)tr * HDIM + c] = acc[i][j][r];
      }
    }
  }
}

extern "C" void kernel_launch(void* const* d_in, const int* in_sizes, int n_in,
                              void* d_out, int out_size, void* d_ws, size_t ws_size,
                              hipStream_t stream) {
  (void)in_sizes; (void)n_in; (void)out_size; (void)ws_size;
  const float* x    = (const float*)d_in[0];
  const float* pos  = (const float*)d_in[1];
  const float* Wqkv = (const float*)d_in[2];
  const float* Wout = (const float*)d_in[3];
  float* out = (float*)d_out;

  char* ws = (char*)d_ws;
  unsigned short* XP   = (unsigned short*)(ws);
  unsigned short* X    = (unsigned short*)(ws + ((size_t)8  << 20));
  unsigned short* WQT  = (unsigned short*)(ws + ((size_t)16 << 20));
  unsigned short* WOT  = (unsigned short*)(ws + ((size_t)22 << 20));
  unsigned short* Qb   = (unsigned short*)(ws + ((size_t)24 << 20));
  unsigned short* Kb   = (unsigned short*)(ws + ((size_t)32 << 20));
  unsigned short* VTb  = (unsigned short*)(ws + ((size_t)40 << 20));
  unsigned short* ATTN = (unsigned short*)(ws + ((size_t)48 << 20));

  prep_all_kernel<<<8192, 256, 0, stream>>>(x, pos, Wqkv, Wout, X, XP, WQT, WOT);

  dim3 g1(TOKENS / 128, 3 * HDIM / 128);
  gemm_qkv_kernel<<<g1, 512, 0, stream>>>(XP, X, WQT, Qb, Kb, VTb);

  dim3 g2(2 * NHEADS, 16);
  attn_pair_kernel<<<g2, 256, 0, stream>>>(Qb, Kb, VTb, ATTN);

  dim3 g3(TOKENS / 128, HDIM / 64);
  gemm_out_kernel<<<g3, 256, 0, stream>>>(ATTN, WOT, out);
}

// Round 4
// 187.725 us; speedup vs baseline: 1.6531x; 1.6531x over previous
//
#include <hip/hip_runtime.h>

#define SEQ     2048
#define HDIM    1024
#define TOKENS  4096   // B*SEQ
#define NHEADS  16
#define HS      64
#define LP      72     // padded LDS row stride (elements): 144B, 16B-aligned

typedef __bf16 v8bf __attribute__((ext_vector_type(8)));
typedef float  v4f  __attribute__((ext_vector_type(4)));

#define MFMA16(a, b, c) __builtin_amdgcn_mfma_f32_16x16x32_bf16((a), (b), (c), 0, 0, 0)

// scores arrive in log2 units: 1/sqrt(64) * log2(e) folded into Q pre-scale
#define QSCALE (0.125f * 1.44269504088896f)

__device__ __forceinline__ unsigned short f2bf(float f) {
  unsigned int u = __float_as_uint(f);
  u += 0x7FFFu + ((u >> 16) & 1u);   // RNE
  return (unsigned short)(u >> 16);
}

__device__ __forceinline__ void async16(const void* g, void* l) {
  __builtin_amdgcn_global_load_lds(
      (const __attribute__((address_space(1))) void*)g,
      (__attribute__((address_space(3))) void*)l, 16, 0, 0);
}

// ---------------- fused prep: x casts + both weight transposes ----------------
__global__ __launch_bounds__(256) void prep_all_kernel(
    const float* __restrict__ x, const float* __restrict__ pos,
    const float* __restrict__ Wqkv, const float* __restrict__ Wout,
    unsigned short* __restrict__ X, unsigned short* __restrict__ XP,
    unsigned short* __restrict__ WQT, unsigned short* __restrict__ WOT) {
  __shared__ float tile[32][33];
  const int id = blockIdx.x;
  if (id < 4096) {
    const int i = (id * 256 + threadIdx.x) * 4;
    float4 xv = *(const float4*)(x + i);
    float4 pv = *(const float4*)(pos + (i & (SEQ * HDIM - 1)));
    ushort4 a, b;
    a.x = f2bf(xv.x); a.y = f2bf(xv.y); a.z = f2bf(xv.z); a.w = f2bf(xv.w);
    b.x = f2bf(xv.x + pv.x); b.y = f2bf(xv.y + pv.y);
    b.z = f2bf(xv.z + pv.z); b.w = f2bf(xv.w + pv.w);
    *(ushort4*)(X + i) = a;
    *(ushort4*)(XP + i) = b;
    return;
  }
  const float* in; unsigned short* out; int R, C, bx, by;
  if (id < 7168) {
    const int t2 = id - 4096;
    in = Wqkv; out = WQT; R = HDIM; C = 3 * HDIM;
    bx = (t2 % 96) * 32; by = (t2 / 96) * 32;
  } else {
    const int t3 = id - 7168;
    in = Wout; out = WOT; R = HDIM; C = HDIM;
    bx = (t3 & 31) * 32; by = (t3 >> 5) * 32;
  }
  const int tx = threadIdx.x & 31, ty = threadIdx.x >> 5;  // (32,8)
#pragma unroll
  for (int j = 0; j < 32; j += 8)
    tile[ty + j][tx] = in[(size_t)(by + ty + j) * C + bx + tx];
  __syncthreads();
#pragma unroll
  for (int j = 0; j < 32; j += 8)
    out[(size_t)(bx + ty + j) * R + by + tx] = f2bf(tile[tx][ty + j]);
}

// ---------------- GEMM1: C(4096x3072) = Aeff(4096x1024) @ Wt(3072x1024)^T ----------------
// EXACT R0 structure (measured 48.1us / 537 TF). R1-R3 established that every
// source-level schedule intervention on this 2-barrier loop regresses
// (vmcnt(0) 2ph: 57us; counted 3-deep: 78us; 512thr+bounds: spill, 177us),
// matching guide m131-m141. Do not touch without a structural (8-phase) port.
// BK=64 (two 32-wide LDS sub-buffers per iter): halves barrier count vs BK=32.
// V blocks compute C^T via operand swap so the V^T store is 32B s-runs.
__global__ __launch_bounds__(256) void gemm_qkv_kernel(
    const unsigned short* __restrict__ XP, const unsigned short* __restrict__ X,
    const unsigned short* __restrict__ Wt,
    unsigned short* __restrict__ Qb, unsigned short* __restrict__ Kb,
    unsigned short* __restrict__ VTb) {
  __shared__ unsigned short As[2][128 * 32];
  __shared__ unsigned short Bs[2][128 * 32];
  const int m0 = blockIdx.x * 128;
  const int n0 = blockIdx.y * 128;
  const bool isV = (n0 >= 2 * HDIM);
  const unsigned short* A = isV ? X : XP;
  const int t = threadIdx.x;
  const int lane = t & 63, w = t >> 6;
  const int wm = (w >> 1) * 64, wn = (w & 1) * 64;
  const int quad = lane >> 4, l15 = lane & 15;

  v4f acc[4][4] = {};

  const int rowA = t >> 2;          // 0..63
  const int colA = (t & 3) * 8;
  const unsigned short* gA = A + (size_t)(m0 + rowA) * HDIM + colA;
  const unsigned short* gB = Wt + (size_t)(n0 + rowA) * HDIM + colA;

  for (int k0 = 0; k0 < HDIM; k0 += 64) {
    __syncthreads();
#pragma unroll
    for (int kh = 0; kh < 2; kh++) {
      async16(gA + k0 + kh * 32, &As[kh][t * 8]);
      async16(gA + 64 * HDIM + k0 + kh * 32, &As[kh][2048 + t * 8]);
      async16(gB + k0 + kh * 32, &Bs[kh][t * 8]);
      async16(gB + 64 * HDIM + k0 + kh * 32, &Bs[kh][2048 + t * 8]);
    }
    __syncthreads();
#pragma unroll
    for (int kh = 0; kh < 2; kh++) {
      v8bf a[4], b[4];
#pragma unroll
      for (int i = 0; i < 4; i++)
        a[i] = *(const v8bf*)&As[kh][(wm + i * 16 + l15) * 32 + quad * 8];
#pragma unroll
      for (int i = 0; i < 4; i++)
        b[i] = *(const v8bf*)&Bs[kh][(wn + i * 16 + l15) * 32 + quad * 8];
      if (isV) {
#pragma unroll
        for (int i = 0; i < 4; i++)
#pragma unroll
          for (int j = 0; j < 4; j++)
            acc[i][j] = MFMA16(b[j], a[i], acc[i][j]);   // C^T
      } else {
#pragma unroll
        for (int i = 0; i < 4; i++)
#pragma unroll
          for (int j = 0; j < 4; j++)
            acc[i][j] = MFMA16(a[i], b[j], acc[i][j]);
      }
    }
  }

  const int b_ = m0 >> 11;
  const int s0 = m0 & (SEQ - 1);

  if (isV) {
    // acc[i][j] = C^T: D[row=quad*4+r -> Wt col (d)][col=l15 -> token (s)]
#pragma unroll
    for (int i = 0; i < 4; i++) {
#pragma unroll
      for (int j = 0; j < 4; j++) {
        const int s_ = s0 + wm + i * 16 + l15;
#pragma unroll
        for (int r = 0; r < 4; r++) {
          const int c2 = (n0 - 2 * HDIM) + wn + j * 16 + quad * 4 + r;
          const int h = c2 >> 6, d = c2 & 63;
          VTb[((size_t)(((b_ << 4) | h) * HS + d)) * SEQ + s_] = f2bf(acc[i][j][r]);
        }
      }
    }
  } else {
    // Q/K[(b,h,s), d]: scatter, 16 consecutive lanes form 32B d-runs
    const float scale = (n0 < HDIM) ? QSCALE : 1.0f;
    unsigned short* dst = (n0 < HDIM) ? Qb : Kb;
#pragma unroll
    for (int i = 0; i < 4; i++) {
#pragma unroll
      for (int j = 0; j < 4; j++) {
#pragma unroll
        for (int r = 0; r < 4; r++) {
          const int s_ = s0 + wm + i * 16 + quad * 4 + r;
          const int c2 = (n0 & (HDIM - 1)) + wn + j * 16 + l15;
          const int h = c2 >> 6, d = c2 & 63;
          dst[((size_t)(((b_ << 4) | h) * SEQ + s_)) * HS + d] =
              f2bf(acc[i][j][r] * scale);
        }
      }
    }
  }
}

// ---------------- flash attention, complementary-pair balanced + Qs/Ps union --------
// Block (bh, p): q-tiles qlo=p and qhi=31-p (64 rows each), one K/V stream over
// chunks 0..qhi; exactly 33 chunk-tiles per block. Qs (dead after fragment
// load) is overlaid by per-wave Ps => LDS 36,864 B => 4 blocks/CU at 88 VGPR.
// NOTE: launch_bounds min-waves MUST stay 2 — forcing 4 caps VGPR at 64 and
// spills ~60MB to scratch (R10: dur 46->109us, WRITE 8->68MB).
__global__ __launch_bounds__(256, 2) void attn_pair_kernel(
    const unsigned short* __restrict__ Qp, const unsigned short* __restrict__ Kp,
    const unsigned short* __restrict__ Vp, unsigned short* __restrict__ ATTN) {
  __shared__ unsigned short SM[18432];       // 36,864 B
  unsigned short* Ks = SM;                   // 64*LP
  unsigned short* Vs = SM + 4608;            // 64*LP (V^T chunk: [d][key])
  unsigned short* QPs = SM + 9216;           // 128*LP union: Qs (init) / Ps (loop)

  const int bh = blockIdx.x;
  const int p  = blockIdx.y;        // 0..15
  const int b_ = bh >> 4, h = bh & 15;
  const int qlo = p, qhi = 31 - p;
  const int q0lo = qlo * 64, q0hi = qhi * 64;
  const int t = threadIdx.x;
  const int lane = t & 63, w = t >> 6;
  const int quad = lane >> 4, l15 = lane & 15;

  const unsigned short* Qg = Qp + (size_t)bh * SEQ * HS;
  const unsigned short* Kg = Kp + (size_t)bh * SEQ * HS;
  const unsigned short* Vg = Vp + (size_t)bh * HS * SEQ;

  const int sr = t >> 3, scol = (t & 7) * 8;
  *(uint4*)&QPs[sr * LP + scol] = *(const uint4*)(Qg + (size_t)(q0lo + sr) * HS + scol);
  *(uint4*)&QPs[(sr + 32) * LP + scol] =
      *(const uint4*)(Qg + (size_t)(q0lo + sr + 32) * HS + scol);
  *(uint4*)&QPs[(sr + 64) * LP + scol] =
      *(const uint4*)(Qg + (size_t)(q0hi + sr) * HS + scol);
  *(uint4*)&QPs[(sr + 96) * LP + scol] =
      *(const uint4*)(Qg + (size_t)(q0hi + sr + 32) * HS + scol);
  __syncthreads();

  // Q rows as B-operand fragments: [tile][khalf]. After these ds_reads drain
  // (at the first in-loop __syncthreads), QPs is reused as per-wave Ps.
  v8bf bq[2][2];
#pragma unroll
  for (int tl = 0; tl < 2; tl++)
#pragma unroll
    for (int kh = 0; kh < 2; kh++)
      bq[tl][kh] = *(const v8bf*)&QPs[(tl * 64 + w * 16 + l15) * LP + kh * 32 + quad * 8];

  unsigned short* Ps_w = QPs + w * 32 * LP;  // 32 rows/wave: 0-15 lo, 16-31 hi

  v8bf ones;
#pragma unroll
  for (int j = 0; j < 8; j++) ones[j] = (__bf16)1.0f;

  v4f o[2][4] = {};
  v4f lacc[2] = {};

  // register prefetch of chunk 0
  uint4 kr0, kr1, vr0, vr1;
  kr0 = *(const uint4*)(Kg + (size_t)sr * HS + scol);
  kr1 = *(const uint4*)(Kg + (size_t)(sr + 32) * HS + scol);
  vr0 = *(const uint4*)(Vg + (size_t)sr * SEQ + scol);
  vr1 = *(const uint4*)(Vg + (size_t)(sr + 32) * SEQ + scol);

  const int qrow_hi = q0hi + w * 16 + l15;  // lane's q-row in S^T
  const int qrow_lo = q0lo + w * 16 + l15;

  for (int cI = 0; cI <= qhi; cI++) {
    const int kc = cI * 64;
    __syncthreads();  // previous chunk's K/V (and init bq) LDS reads done
    *(uint4*)&Ks[sr * LP + scol] = kr0;
    *(uint4*)&Ks[(sr + 32) * LP + scol] = kr1;
    *(uint4*)&Vs[sr * LP + scol] = vr0;
    *(uint4*)&Vs[(sr + 32) * LP + scol] = vr1;
    if (cI < qhi) {  // prefetch next chunk while computing this one
      const int kn = kc + 64;
      kr0 = *(const uint4*)(Kg + (size_t)(kn + sr) * HS + scol);
      kr1 = *(const uint4*)(Kg + (size_t)(kn + sr + 32) * HS + scol);
      vr0 = *(const uint4*)(Vg + (size_t)sr * SEQ + kn + scol);
      vr1 = *(const uint4*)(Vg + (size_t)(sr + 32) * SEQ + kn + scol);
    }
    __syncthreads();

    // K fragments (A-operand), shared across both tiles
    v8bf kf0[4], kf1[4];
#pragma unroll
    for (int ni = 0; ni < 4; ni++) {
      kf0[ni] = *(const v8bf*)&Ks[(ni * 16 + l15) * LP + quad * 8];
      kf1[ni] = *(const v8bf*)&Ks[(ni * 16 + l15) * LP + 32 + quad * 8];
    }

    const bool doLo = (cI <= qlo);

    // ---- hi tile: S^T = K Q^T, D[key=quad*4+r][qrow=l15] ----
    {
      v4f sc[4] = {};
#pragma unroll
      for (int ni = 0; ni < 4; ni++) {
        sc[ni] = MFMA16(kf0[ni], bq[1][0], sc[ni]);
        sc[ni] = MFMA16(kf1[ni], bq[1][1], sc[ni]);
      }
      if (cI == qhi) {
#pragma unroll
        for (int ni = 0; ni < 4; ni++) {
          const int key = kc + ni * 16 + quad * 4;
#pragma unroll
          for (int r = 0; r < 4; r++)
            if (key + r > qrow_hi) sc[ni][r] = -1e30f;
        }
      }
#pragma unroll
      for (int ni = 0; ni < 4; ni++) {
        const float p0 = exp2f(sc[ni][0]), p1 = exp2f(sc[ni][1]);
        const float p2 = exp2f(sc[ni][2]), p3 = exp2f(sc[ni][3]);
        uint2 pk;
        pk.x = __builtin_amdgcn_perm(__float_as_uint(p1), __float_as_uint(p0), 0x07060302u);
        pk.y = __builtin_amdgcn_perm(__float_as_uint(p3), __float_as_uint(p2), 0x07060302u);
        *(uint2*)&Ps_w[(16 + l15) * LP + ni * 16 + quad * 4] = pk;
      }
    }
    // ---- lo tile (wave-uniform skip once cI > qlo) ----
    if (doLo) {
      v4f sc[4] = {};
#pragma unroll
      for (int ni = 0; ni < 4; ni++) {
        sc[ni] = MFMA16(kf0[ni], bq[0][0], sc[ni]);
        sc[ni] = MFMA16(kf1[ni], bq[0][1], sc[ni]);
      }
      if (cI == qlo) {
#pragma unroll
        for (int ni = 0; ni < 4; ni++) {
          const int key = kc + ni * 16 + quad * 4;
#pragma unroll
          for (int r = 0; r < 4; r++)
            if (key + r > qrow_lo) sc[ni][r] = -1e30f;
        }
      }
#pragma unroll
      for (int ni = 0; ni < 4; ni++) {
        const float p0 = exp2f(sc[ni][0]), p1 = exp2f(sc[ni][1]);
        const float p2 = exp2f(sc[ni][2]), p3 = exp2f(sc[ni][3]);
        uint2 pk;
        pk.x = __builtin_amdgcn_perm(__float_as_uint(p1), __float_as_uint(p0), 0x07060302u);
        pk.y = __builtin_amdgcn_perm(__float_as_uint(p3), __float_as_uint(p2), 0x07060302u);
        *(uint2*)&Ps_w[l15 * LP + ni * 16 + quad * 4] = pk;
      }
    }

    // ---- O += P @ V, l += P @ 1; V fragments shared across tiles ----
#pragma unroll
    for (int ki = 0; ki < 2; ki++) {
      v8bf pahi = *(const v8bf*)&Ps_w[(16 + l15) * LP + ki * 32 + quad * 8];
      lacc[1] = MFMA16(pahi, ones, lacc[1]);
      v8bf palo;
      if (doLo) {
        palo = *(const v8bf*)&Ps_w[l15 * LP + ki * 32 + quad * 8];
        lacc[0] = MFMA16(palo, ones, lacc[0]);
      }
#pragma unroll
      for (int ni = 0; ni < 4; ni++) {
        v8bf vb = *(const v8bf*)&Vs[(ni * 16 + l15) * LP + ki * 32 + quad * 8];
        o[1][ni] = MFMA16(pahi, vb, o[1][ni]);
        if (doLo) o[0][ni] = MFMA16(palo, vb, o[0][ni]);
      }
    }
  }

  // epilogue: normalize and store both tiles (C-layout rows = quad*4+r)
#pragma unroll
  for (int tl = 0; tl < 2; tl++) {
    const int q0 = tl ? q0hi : q0lo;
    const int row_base = q0 + w * 16 + quad * 4;
    float invl[4];
#pragma unroll
    for (int r = 0; r < 4; r++) invl[r] = 1.0f / lacc[tl][r];
#pragma unroll
    for (int ni = 0; ni < 4; ni++)
#pragma unroll
      for (int r = 0; r < 4; r++) {
        const int tr = b_ * SEQ + row_base + r;
        ATTN[(size_t)tr * HDIM + h * HS + ni * 16 + l15] = f2bf(o[tl][ni][r] * invl[r]);
      }
  }
}

// ---------------- GEMM2: out(4096x1024) = ATTN @ WOT^T, fp32 out ----------------
// 128x64 tiles -> 512 blocks (2/CU); 3-deep counted-vmcnt pipeline (KEPT:
// at 2 blocks/CU there is no inter-block overlap, so the explicit pipeline is
// what hides load latency here — R1 within-run delta: ~-9us on this kernel).
__global__ __launch_bounds__(256) void gemm_out_kernel(
    const unsigned short* __restrict__ Ab, const unsigned short* __restrict__ Wt,
    float* __restrict__ out) {
  __shared__ unsigned short As[3][128 * 32];
  __shared__ unsigned short Bs[3][64 * 32];
  const int m0 = blockIdx.x * 128;
  const int n0 = blockIdx.y * 64;
  const int t = threadIdx.x;
  const int lane = t & 63, w = t >> 6;
  const int wm = w * 32;
  const int quad = lane >> 4, l15 = lane & 15;

  v4f acc[2][4] = {};

  const int rowA = t >> 2;
  const int colA = (t & 3) * 8;
  const unsigned short* gA = Ab + (size_t)(m0 + rowA) * HDIM + colA;
  const unsigned short* gB = Wt + (size_t)(n0 + rowA) * HDIM + colA;

  auto issue = [&](int k0, int buf) {
    async16(gA + k0, &As[buf][t * 8]);
    async16(gA + 64 * HDIM + k0, &As[buf][2048 + t * 8]);
    async16(gB + k0, &Bs[buf][t * 8]);   // rowA is always <64: all threads load B
  };
  auto compute = [&](int buf) {
    v8bf a[2], b[4];
#pragma unroll
    for (int i = 0; i < 2; i++)
      a[i] = *(const v8bf*)&As[buf][(wm + i * 16 + l15) * 32 + quad * 8];
#pragma unroll
    for (int j = 0; j < 4; j++)
      b[j] = *(const v8bf*)&Bs[buf][(j * 16 + l15) * 32 + quad * 8];
#pragma unroll
    for (int i = 0; i < 2; i++)
#pragma unroll
      for (int j = 0; j < 4; j++)
        acc[i][j] = MFMA16(a[i], b[j], acc[i][j]);
  };

  issue(0, 0);
  issue(32, 1);
  asm volatile("s_waitcnt vmcnt(3)" ::: "memory");
  __builtin_amdgcn_s_barrier();
  asm volatile("" ::: "memory");

  int cur = 0;
#pragma unroll 3
  for (int kt = 0; kt < 30; ++kt) {
    int ib = cur + 2; if (ib >= 3) ib -= 3;
    issue((kt + 2) * 32, ib);
    compute(cur);
    asm volatile("s_waitcnt vmcnt(3)" ::: "memory");
    __builtin_amdgcn_s_barrier();
    asm volatile("" ::: "memory");
    if (++cur == 3) cur = 0;
  }
  compute(cur);
  asm volatile("s_waitcnt vmcnt(0)" ::: "memory");
  __builtin_amdgcn_s_barrier();
  asm volatile("" ::: "memory");
  if (++cur == 3) cur = 0;
  compute(cur);

#pragma unroll
  for (int i = 0; i < 2; i++) {
#pragma unroll
    for (int j = 0; j < 4; j++) {
#pragma unroll
      for (int r = 0; r < 4; r++) {
        const int tr = m0 + wm + i * 16 + quad * 4 + r;
        const int c = n0 + j * 16 + l15;
        out[(size_t)tr * HDIM + c] = acc[i][j][r];
      }
    }
  }
}

extern "C" void kernel_launch(void* const* d_in, const int* in_sizes, int n_in,
                              void* d_out, int out_size, void* d_ws, size_t ws_size,
                              hipStream_t stream) {
  (void)in_sizes; (void)n_in; (void)out_size; (void)ws_size;
  const float* x    = (const float*)d_in[0];
  const float* pos  = (const float*)d_in[1];
  const float* Wqkv = (const float*)d_in[2];
  const float* Wout = (const float*)d_in[3];
  float* out = (float*)d_out;

  char* ws = (char*)d_ws;
  unsigned short* XP   = (unsigned short*)(ws);
  unsigned short* X    = (unsigned short*)(ws + ((size_t)8  << 20));
  unsigned short* WQT  = (unsigned short*)(ws + ((size_t)16 << 20));
  unsigned short* WOT  = (unsigned short*)(ws + ((size_t)22 << 20));
  unsigned short* Qb   = (unsigned short*)(ws + ((size_t)24 << 20));
  unsigned short* Kb   = (unsigned short*)(ws + ((size_t)32 << 20));
  unsigned short* VTb  = (unsigned short*)(ws + ((size_t)40 << 20));
  unsigned short* ATTN = (unsigned short*)(ws + ((size_t)48 << 20));

  prep_all_kernel<<<8192, 256, 0, stream>>>(x, pos, Wqkv, Wout, X, XP, WQT, WOT);

  dim3 g1(TOKENS / 128, 3 * HDIM / 128);
  gemm_qkv_kernel<<<g1, 256, 0, stream>>>(XP, X, WQT, Qb, Kb, VTb);

  dim3 g2(2 * NHEADS, 16);
  attn_pair_kernel<<<g2, 256, 0, stream>>>(Qb, Kb, VTb, ATTN);

  dim3 g3(TOKENS / 128, HDIM / 64);
  gemm_out_kernel<<<g3, 256, 0, stream>>>(ATTN, WOT, out);
}

// Round 5
// 186.629 us; speedup vs baseline: 1.6628x; 1.0059x over previous
//
#include <hip/hip_runtime.h>

#define SEQ     2048
#define HDIM    1024
#define TOKENS  4096   // B*SEQ
#define NHEADS  16
#define HS      64
#define LP      72     // padded LDS row stride (elements): 144B, 16B-aligned

typedef __bf16 v8bf __attribute__((ext_vector_type(8)));
typedef float  v4f  __attribute__((ext_vector_type(4)));

#define MFMA16(a, b, c) __builtin_amdgcn_mfma_f32_16x16x32_bf16((a), (b), (c), 0, 0, 0)

// scores arrive in log2 units: 1/sqrt(64) * log2(e) folded into Q pre-scale
#define QSCALE (0.125f * 1.44269504088896f)

__device__ __forceinline__ unsigned short f2bf(float f) {
  unsigned int u = __float_as_uint(f);
  u += 0x7FFFu + ((u >> 16) & 1u);   // RNE
  return (unsigned short)(u >> 16);
}

__device__ __forceinline__ void async16(const void* g, void* l) {
  __builtin_amdgcn_global_load_lds(
      (const __attribute__((address_space(1))) void*)g,
      (__attribute__((address_space(3))) void*)l, 16, 0, 0);
}

// ---------------- fused prep: x casts + both weight transposes ----------------
__global__ __launch_bounds__(256) void prep_all_kernel(
    const float* __restrict__ x, const float* __restrict__ pos,
    const float* __restrict__ Wqkv, const float* __restrict__ Wout,
    unsigned short* __restrict__ X, unsigned short* __restrict__ XP,
    unsigned short* __restrict__ WQT, unsigned short* __restrict__ WOT) {
  __shared__ float tile[32][33];
  const int id = blockIdx.x;
  if (id < 4096) {
    const int i = (id * 256 + threadIdx.x) * 4;
    float4 xv = *(const float4*)(x + i);
    float4 pv = *(const float4*)(pos + (i & (SEQ * HDIM - 1)));
    ushort4 a, b;
    a.x = f2bf(xv.x); a.y = f2bf(xv.y); a.z = f2bf(xv.z); a.w = f2bf(xv.w);
    b.x = f2bf(xv.x + pv.x); b.y = f2bf(xv.y + pv.y);
    b.z = f2bf(xv.z + pv.z); b.w = f2bf(xv.w + pv.w);
    *(ushort4*)(X + i) = a;
    *(ushort4*)(XP + i) = b;
    return;
  }
  const float* in; unsigned short* out; int R, C, bx, by;
  if (id < 7168) {
    const int t2 = id - 4096;
    in = Wqkv; out = WQT; R = HDIM; C = 3 * HDIM;
    bx = (t2 % 96) * 32; by = (t2 / 96) * 32;
  } else {
    const int t3 = id - 7168;
    in = Wout; out = WOT; R = HDIM; C = HDIM;
    bx = (t3 & 31) * 32; by = (t3 >> 5) * 32;
  }
  const int tx = threadIdx.x & 31, ty = threadIdx.x >> 5;  // (32,8)
#pragma unroll
  for (int j = 0; j < 32; j += 8)
    tile[ty + j][tx] = in[(size_t)(by + ty + j) * C + bx + tx];
  __syncthreads();
#pragma unroll
  for (int j = 0; j < 32; j += 8)
    out[(size_t)(bx + ty + j) * R + by + tx] = f2bf(tile[tx][ty + j]);
}

// ---------------- GEMM1: C(4096x3072) = Aeff(4096x1024) @ Wt(3072x1024)^T ----------------
// R0 serial 2-barrier structure (measured 45.7-48.1us; R1-R3 schedule tweaks
// all regressed — see journal). NEW in R5: 2D-patch XCD swizzle. HW round-robins
// linear wg-id across 8 XCDs (orig%8=xcd). Accidental mapping gave each XCD
// A=1MB (fits 4MB L2) but B=all 24 panels=6MB -> L2 thrash on B, staging
// traffic (~400MB total) served from L3 -> latency+BW wall. Patch mapping
// gives each XCD 8m x 12n (A 2MB + B 3MB = 5MB) -> most re-reads L2-hit.
// Bijective: 768 blocks = 8 XCDs x 96.
// V blocks compute C^T via operand swap so the V^T store is 32B s-runs.
__global__ __launch_bounds__(256) void gemm_qkv_kernel(
    const unsigned short* __restrict__ XP, const unsigned short* __restrict__ X,
    const unsigned short* __restrict__ Wt,
    unsigned short* __restrict__ Qb, unsigned short* __restrict__ Kb,
    unsigned short* __restrict__ VTb) {
  __shared__ unsigned short As[2][128 * 32];
  __shared__ unsigned short Bs[2][128 * 32];
  const int orig = blockIdx.y * gridDim.x + blockIdx.x;   // 0..767
  const int xcd = orig & 7, idx = orig >> 3;              // idx 0..95
  const int mt = (xcd & 3) * 8 + (idx & 7);               // 0..31
  const int nt = (xcd >> 2) * 12 + (idx >> 3);            // 0..23
  const int m0 = mt * 128;
  const int n0 = nt * 128;
  const bool isV = (n0 >= 2 * HDIM);
  const unsigned short* A = isV ? X : XP;
  const int t = threadIdx.x;
  const int lane = t & 63, w = t >> 6;
  const int wm = (w >> 1) * 64, wn = (w & 1) * 64;
  const int quad = lane >> 4, l15 = lane & 15;

  v4f acc[4][4] = {};

  const int rowA = t >> 2;          // 0..63
  const int colA = (t & 3) * 8;
  const unsigned short* gA = A + (size_t)(m0 + rowA) * HDIM + colA;
  const unsigned short* gB = Wt + (size_t)(n0 + rowA) * HDIM + colA;

  for (int k0 = 0; k0 < HDIM; k0 += 64) {
    __syncthreads();
#pragma unroll
    for (int kh = 0; kh < 2; kh++) {
      async16(gA + k0 + kh * 32, &As[kh][t * 8]);
      async16(gA + 64 * HDIM + k0 + kh * 32, &As[kh][2048 + t * 8]);
      async16(gB + k0 + kh * 32, &Bs[kh][t * 8]);
      async16(gB + 64 * HDIM + k0 + kh * 32, &Bs[kh][2048 + t * 8]);
    }
    __syncthreads();
#pragma unroll
    for (int kh = 0; kh < 2; kh++) {
      v8bf a[4], b[4];
#pragma unroll
      for (int i = 0; i < 4; i++)
        a[i] = *(const v8bf*)&As[kh][(wm + i * 16 + l15) * 32 + quad * 8];
#pragma unroll
      for (int i = 0; i < 4; i++)
        b[i] = *(const v8bf*)&Bs[kh][(wn + i * 16 + l15) * 32 + quad * 8];
      if (isV) {
#pragma unroll
        for (int i = 0; i < 4; i++)
#pragma unroll
          for (int j = 0; j < 4; j++)
            acc[i][j] = MFMA16(b[j], a[i], acc[i][j]);   // C^T
      } else {
#pragma unroll
        for (int i = 0; i < 4; i++)
#pragma unroll
          for (int j = 0; j < 4; j++)
            acc[i][j] = MFMA16(a[i], b[j], acc[i][j]);
      }
    }
  }

  const int b_ = m0 >> 11;
  const int s0 = m0 & (SEQ - 1);

  if (isV) {
    // acc[i][j] = C^T: D[row=quad*4+r -> Wt col (d)][col=l15 -> token (s)]
#pragma unroll
    for (int i = 0; i < 4; i++) {
#pragma unroll
      for (int j = 0; j < 4; j++) {
        const int s_ = s0 + wm + i * 16 + l15;
#pragma unroll
        for (int r = 0; r < 4; r++) {
          const int c2 = (n0 - 2 * HDIM) + wn + j * 16 + quad * 4 + r;
          const int h = c2 >> 6, d = c2 & 63;
          VTb[((size_t)(((b_ << 4) | h) * HS + d)) * SEQ + s_] = f2bf(acc[i][j][r]);
        }
      }
    }
  } else {
    // Q/K[(b,h,s), d]: scatter, 16 consecutive lanes form 32B d-runs
    const float scale = (n0 < HDIM) ? QSCALE : 1.0f;
    unsigned short* dst = (n0 < HDIM) ? Qb : Kb;
#pragma unroll
    for (int i = 0; i < 4; i++) {
#pragma unroll
      for (int j = 0; j < 4; j++) {
#pragma unroll
        for (int r = 0; r < 4; r++) {
          const int s_ = s0 + wm + i * 16 + quad * 4 + r;
          const int c2 = (n0 & (HDIM - 1)) + wn + j * 16 + l15;
          const int h = c2 >> 6, d = c2 & 63;
          dst[((size_t)(((b_ << 4) | h) * SEQ + s_)) * HS + d] =
              f2bf(acc[i][j][r] * scale);
        }
      }
    }
  }
}

// ---------------- flash attention, complementary-pair balanced + Qs/Ps union --------
// Block (bh, p): q-tiles qlo=p and qhi=31-p (64 rows each), one K/V stream over
// chunks 0..qhi; exactly 33 chunk-tiles per block. Qs (dead after fragment
// load) is overlaid by per-wave Ps => LDS 36,864 B => 4 blocks/CU at 88 VGPR.
// NOTE: launch_bounds min-waves MUST stay 2 — forcing 4 caps VGPR at 64 and
// spills ~60MB to scratch (R10: dur 46->109us, WRITE 8->68MB).
// (Accidental XCD mapping already localizes K/V: bh = orig%32 -> each XCD gets
// 4 bh x 512KB = 2MB, L2-fit. Leave as-is.)
__global__ __launch_bounds__(256, 2) void attn_pair_kernel(
    const unsigned short* __restrict__ Qp, const unsigned short* __restrict__ Kp,
    const unsigned short* __restrict__ Vp, unsigned short* __restrict__ ATTN) {
  __shared__ unsigned short SM[18432];       // 36,864 B
  unsigned short* Ks = SM;                   // 64*LP
  unsigned short* Vs = SM + 4608;            // 64*LP (V^T chunk: [d][key])
  unsigned short* QPs = SM + 9216;           // 128*LP union: Qs (init) / Ps (loop)

  const int bh = blockIdx.x;
  const int p  = blockIdx.y;        // 0..15
  const int b_ = bh >> 4, h = bh & 15;
  const int qlo = p, qhi = 31 - p;
  const int q0lo = qlo * 64, q0hi = qhi * 64;
  const int t = threadIdx.x;
  const int lane = t & 63, w = t >> 6;
  const int quad = lane >> 4, l15 = lane & 15;

  const unsigned short* Qg = Qp + (size_t)bh * SEQ * HS;
  const unsigned short* Kg = Kp + (size_t)bh * SEQ * HS;
  const unsigned short* Vg = Vp + (size_t)bh * HS * SEQ;

  const int sr = t >> 3, scol = (t & 7) * 8;
  *(uint4*)&QPs[sr * LP + scol] = *(const uint4*)(Qg + (size_t)(q0lo + sr) * HS + scol);
  *(uint4*)&QPs[(sr + 32) * LP + scol] =
      *(const uint4*)(Qg + (size_t)(q0lo + sr + 32) * HS + scol);
  *(uint4*)&QPs[(sr + 64) * LP + scol] =
      *(const uint4*)(Qg + (size_t)(q0hi + sr) * HS + scol);
  *(uint4*)&QPs[(sr + 96) * LP + scol] =
      *(const uint4*)(Qg + (size_t)(q0hi + sr + 32) * HS + scol);
  __syncthreads();

  // Q rows as B-operand fragments: [tile][khalf]. After these ds_reads drain
  // (at the first in-loop __syncthreads), QPs is reused as per-wave Ps.
  v8bf bq[2][2];
#pragma unroll
  for (int tl = 0; tl < 2; tl++)
#pragma unroll
    for (int kh = 0; kh < 2; kh++)
      bq[tl][kh] = *(const v8bf*)&QPs[(tl * 64 + w * 16 + l15) * LP + kh * 32 + quad * 8];

  unsigned short* Ps_w = QPs + w * 32 * LP;  // 32 rows/wave: 0-15 lo, 16-31 hi

  v8bf ones;
#pragma unroll
  for (int j = 0; j < 8; j++) ones[j] = (__bf16)1.0f;

  v4f o[2][4] = {};
  v4f lacc[2] = {};

  // register prefetch of chunk 0
  uint4 kr0, kr1, vr0, vr1;
  kr0 = *(const uint4*)(Kg + (size_t)sr * HS + scol);
  kr1 = *(const uint4*)(Kg + (size_t)(sr + 32) * HS + scol);
  vr0 = *(const uint4*)(Vg + (size_t)sr * SEQ + scol);
  vr1 = *(const uint4*)(Vg + (size_t)(sr + 32) * SEQ + scol);

  const int qrow_hi = q0hi + w * 16 + l15;  // lane's q-row in S^T
  const int qrow_lo = q0lo + w * 16 + l15;

  for (int cI = 0; cI <= qhi; cI++) {
    const int kc = cI * 64;
    __syncthreads();  // previous chunk's K/V (and init bq) LDS reads done
    *(uint4*)&Ks[sr * LP + scol] = kr0;
    *(uint4*)&Ks[(sr + 32) * LP + scol] = kr1;
    *(uint4*)&Vs[sr * LP + scol] = vr0;
    *(uint4*)&Vs[(sr + 32) * LP + scol] = vr1;
    if (cI < qhi) {  // prefetch next chunk while computing this one
      const int kn = kc + 64;
      kr0 = *(const uint4*)(Kg + (size_t)(kn + sr) * HS + scol);
      kr1 = *(const uint4*)(Kg + (size_t)(kn + sr + 32) * HS + scol);
      vr0 = *(const uint4*)(Vg + (size_t)sr * SEQ + kn + scol);
      vr1 = *(const uint4*)(Vg + (size_t)(sr + 32) * SEQ + kn + scol);
    }
    __syncthreads();

    // K fragments (A-operand), shared across both tiles
    v8bf kf0[4], kf1[4];
#pragma unroll
    for (int ni = 0; ni < 4; ni++) {
      kf0[ni] = *(const v8bf*)&Ks[(ni * 16 + l15) * LP + quad * 8];
      kf1[ni] = *(const v8bf*)&Ks[(ni * 16 + l15) * LP + 32 + quad * 8];
    }

    const bool doLo = (cI <= qlo);

    // ---- hi tile: S^T = K Q^T, D[key=quad*4+r][qrow=l15] ----
    {
      v4f sc[4] = {};
#pragma unroll
      for (int ni = 0; ni < 4; ni++) {
        sc[ni] = MFMA16(kf0[ni], bq[1][0], sc[ni]);
        sc[ni] = MFMA16(kf1[ni], bq[1][1], sc[ni]);
      }
      if (cI == qhi) {
#pragma unroll
        for (int ni = 0; ni < 4; ni++) {
          const int key = kc + ni * 16 + quad * 4;
#pragma unroll
          for (int r = 0; r < 4; r++)
            if (key + r > qrow_hi) sc[ni][r] = -1e30f;
        }
      }
#pragma unroll
      for (int ni = 0; ni < 4; ni++) {
        const float p0 = exp2f(sc[ni][0]), p1 = exp2f(sc[ni][1]);
        const float p2 = exp2f(sc[ni][2]), p3 = exp2f(sc[ni][3]);
        uint2 pk;
        pk.x = __builtin_amdgcn_perm(__float_as_uint(p1), __float_as_uint(p0), 0x07060302u);
        pk.y = __builtin_amdgcn_perm(__float_as_uint(p3), __float_as_uint(p2), 0x07060302u);
        *(uint2*)&Ps_w[(16 + l15) * LP + ni * 16 + quad * 4] = pk;
      }
    }
    // ---- lo tile (wave-uniform skip once cI > qlo) ----
    if (doLo) {
      v4f sc[4] = {};
#pragma unroll
      for (int ni = 0; ni < 4; ni++) {
        sc[ni] = MFMA16(kf0[ni], bq[0][0], sc[ni]);
        sc[ni] = MFMA16(kf1[ni], bq[0][1], sc[ni]);
      }
      if (cI == qlo) {
#pragma unroll
        for (int ni = 0; ni < 4; ni++) {
          const int key = kc + ni * 16 + quad * 4;
#pragma unroll
          for (int r = 0; r < 4; r++)
            if (key + r > qrow_lo) sc[ni][r] = -1e30f;
        }
      }
#pragma unroll
      for (int ni = 0; ni < 4; ni++) {
        const float p0 = exp2f(sc[ni][0]), p1 = exp2f(sc[ni][1]);
        const float p2 = exp2f(sc[ni][2]), p3 = exp2f(sc[ni][3]);
        uint2 pk;
        pk.x = __builtin_amdgcn_perm(__float_as_uint(p1), __float_as_uint(p0), 0x07060302u);
        pk.y = __builtin_amdgcn_perm(__float_as_uint(p3), __float_as_uint(p2), 0x07060302u);
        *(uint2*)&Ps_w[l15 * LP + ni * 16 + quad * 4] = pk;
      }
    }

    // ---- O += P @ V, l += P @ 1; V fragments shared across tiles ----
#pragma unroll
    for (int ki = 0; ki < 2; ki++) {
      v8bf pahi = *(const v8bf*)&Ps_w[(16 + l15) * LP + ki * 32 + quad * 8];
      lacc[1] = MFMA16(pahi, ones, lacc[1]);
      v8bf palo;
      if (doLo) {
        palo = *(const v8bf*)&Ps_w[l15 * LP + ki * 32 + quad * 8];
        lacc[0] = MFMA16(palo, ones, lacc[0]);
      }
#pragma unroll
      for (int ni = 0; ni < 4; ni++) {
        v8bf vb = *(const v8bf*)&Vs[(ni * 16 + l15) * LP + ki * 32 + quad * 8];
        o[1][ni] = MFMA16(pahi, vb, o[1][ni]);
        if (doLo) o[0][ni] = MFMA16(palo, vb, o[0][ni]);
      }
    }
  }

  // epilogue: normalize and store both tiles (C-layout rows = quad*4+r)
#pragma unroll
  for (int tl = 0; tl < 2; tl++) {
    const int q0 = tl ? q0hi : q0lo;
    const int row_base = q0 + w * 16 + quad * 4;
    float invl[4];
#pragma unroll
    for (int r = 0; r < 4; r++) invl[r] = 1.0f / lacc[tl][r];
#pragma unroll
    for (int ni = 0; ni < 4; ni++)
#pragma unroll
      for (int r = 0; r < 4; r++) {
        const int tr = b_ * SEQ + row_base + r;
        ATTN[(size_t)tr * HDIM + h * HS + ni * 16 + l15] = f2bf(o[tl][ni][r] * invl[r]);
      }
  }
}

// ---------------- GEMM2: out(4096x1024) = ATTN @ WOT^T, fp32 out ----------------
// 128x64 tiles -> 512 blocks (2/CU); 3-deep counted-vmcnt pipeline (neutral vs
// R0's simple loop per R4 totals; kept unchanged this round for attribution).
__global__ __launch_bounds__(256) void gemm_out_kernel(
    const unsigned short* __restrict__ Ab, const unsigned short* __restrict__ Wt,
    float* __restrict__ out) {
  __shared__ unsigned short As[3][128 * 32];
  __shared__ unsigned short Bs[3][64 * 32];
  const int m0 = blockIdx.x * 128;
  const int n0 = blockIdx.y * 64;
  const int t = threadIdx.x;
  const int lane = t & 63, w = t >> 6;
  const int wm = w * 32;
  const int quad = lane >> 4, l15 = lane & 15;

  v4f acc[2][4] = {};

  const int rowA = t >> 2;
  const int colA = (t & 3) * 8;
  const unsigned short* gA = Ab + (size_t)(m0 + rowA) * HDIM + colA;
  const unsigned short* gB = Wt + (size_t)(n0 + rowA) * HDIM + colA;

  auto issue = [&](int k0, int buf) {
    async16(gA + k0, &As[buf][t * 8]);
    async16(gA + 64 * HDIM + k0, &As[buf][2048 + t * 8]);
    async16(gB + k0, &Bs[buf][t * 8]);   // rowA is always <64: all threads load B
  };
  auto compute = [&](int buf) {
    v8bf a[2], b[4];
#pragma unroll
    for (int i = 0; i < 2; i++)
      a[i] = *(const v8bf*)&As[buf][(wm + i * 16 + l15) * 32 + quad * 8];
#pragma unroll
    for (int j = 0; j < 4; j++)
      b[j] = *(const v8bf*)&Bs[buf][(j * 16 + l15) * 32 + quad * 8];
#pragma unroll
    for (int i = 0; i < 2; i++)
#pragma unroll
      for (int j = 0; j < 4; j++)
        acc[i][j] = MFMA16(a[i], b[j], acc[i][j]);
  };

  issue(0, 0);
  issue(32, 1);
  asm volatile("s_waitcnt vmcnt(3)" ::: "memory");
  __builtin_amdgcn_s_barrier();
  asm volatile("" ::: "memory");

  int cur = 0;
#pragma unroll 3
  for (int kt = 0; kt < 30; ++kt) {
    int ib = cur + 2; if (ib >= 3) ib -= 3;
    issue((kt + 2) * 32, ib);
    compute(cur);
    asm volatile("s_waitcnt vmcnt(3)" ::: "memory");
    __builtin_amdgcn_s_barrier();
    asm volatile("" ::: "memory");
    if (++cur == 3) cur = 0;
  }
  compute(cur);
  asm volatile("s_waitcnt vmcnt(0)" ::: "memory");
  __builtin_amdgcn_s_barrier();
  asm volatile("" ::: "memory");
  if (++cur == 3) cur = 0;
  compute(cur);

#pragma unroll
  for (int i = 0; i < 2; i++) {
#pragma unroll
    for (int j = 0; j < 4; j++) {
#pragma unroll
      for (int r = 0; r < 4; r++) {
        const int tr = m0 + wm + i * 16 + quad * 4 + r;
        const int c = n0 + j * 16 + l15;
        out[(size_t)tr * HDIM + c] = acc[i][j][r];
      }
    }
  }
}

extern "C" void kernel_launch(void* const* d_in, const int* in_sizes, int n_in,
                              void* d_out, int out_size, void* d_ws, size_t ws_size,
                              hipStream_t stream) {
  (void)in_sizes; (void)n_in; (void)out_size; (void)ws_size;
  const float* x    = (const float*)d_in[0];
  const float* pos  = (const float*)d_in[1];
  const float* Wqkv = (const float*)d_in[2];
  const float* Wout = (const float*)d_in[3];
  float* out = (float*)d_out;

  char* ws = (char*)d_ws;
  unsigned short* XP   = (unsigned short*)(ws);
  unsigned short* X    = (unsigned short*)(ws + ((size_t)8  << 20));
  unsigned short* WQT  = (unsigned short*)(ws + ((size_t)16 << 20));
  unsigned short* WOT  = (unsigned short*)(ws + ((size_t)22 << 20));
  unsigned short* Qb   = (unsigned short*)(ws + ((size_t)24 << 20));
  unsigned short* Kb   = (unsigned short*)(ws + ((size_t)32 << 20));
  unsigned short* VTb  = (unsigned short*)(ws + ((size_t)40 << 20));
  unsigned short* ATTN = (unsigned short*)(ws + ((size_t)48 << 20));

  prep_all_kernel<<<8192, 256, 0, stream>>>(x, pos, Wqkv, Wout, X, XP, WQT, WOT);

  dim3 g1(TOKENS / 128, 3 * HDIM / 128);
  gemm_qkv_kernel<<<g1, 256, 0, stream>>>(XP, X, WQT, Qb, Kb, VTb);

  dim3 g2(2 * NHEADS, 16);
  attn_pair_kernel<<<g2, 256, 0, stream>>>(Qb, Kb, VTb, ATTN);

  dim3 g3(TOKENS / 128, HDIM / 64);
  gemm_out_kernel<<<g3, 256, 0, stream>>>(ATTN, WOT, out);
}

// Round 6
// 184.578 us; speedup vs baseline: 1.6813x; 1.0111x over previous
//
#include <hip/hip_runtime.h>

#define SEQ     2048
#define HDIM    1024
#define TOKENS  4096   // B*SEQ
#define NHEADS  16
#define HS      64
#define LP      72     // padded LDS row stride (elements): 144B, 16B-aligned

typedef __bf16 v8bf __attribute__((ext_vector_type(8)));
typedef float  v4f  __attribute__((ext_vector_type(4)));

#define MFMA16(a, b, c) __builtin_amdgcn_mfma_f32_16x16x32_bf16((a), (b), (c), 0, 0, 0)

// scores arrive in log2 units: 1/sqrt(64) * log2(e) folded into Q pre-scale
#define QSCALE (0.125f * 1.44269504088896f)

__device__ __forceinline__ unsigned short f2bf(float f) {
  unsigned int u = __float_as_uint(f);
  u += 0x7FFFu + ((u >> 16) & 1u);   // RNE
  return (unsigned short)(u >> 16);
}

__device__ __forceinline__ void async16(const void* g, void* l) {
  __builtin_amdgcn_global_load_lds(
      (const __attribute__((address_space(1))) void*)g,
      (__attribute__((address_space(3))) void*)l, 16, 0, 0);
}

// ---------------- fused prep: x casts + both weight transposes ----------------
__global__ __launch_bounds__(256) void prep_all_kernel(
    const float* __restrict__ x, const float* __restrict__ pos,
    const float* __restrict__ Wqkv, const float* __restrict__ Wout,
    unsigned short* __restrict__ X, unsigned short* __restrict__ XP,
    unsigned short* __restrict__ WQT, unsigned short* __restrict__ WOT) {
  __shared__ float tile[32][33];
  const int id = blockIdx.x;
  if (id < 4096) {
    const int i = (id * 256 + threadIdx.x) * 4;
    float4 xv = *(const float4*)(x + i);
    float4 pv = *(const float4*)(pos + (i & (SEQ * HDIM - 1)));
    ushort4 a, b;
    a.x = f2bf(xv.x); a.y = f2bf(xv.y); a.z = f2bf(xv.z); a.w = f2bf(xv.w);
    b.x = f2bf(xv.x + pv.x); b.y = f2bf(xv.y + pv.y);
    b.z = f2bf(xv.z + pv.z); b.w = f2bf(xv.w + pv.w);
    *(ushort4*)(X + i) = a;
    *(ushort4*)(XP + i) = b;
    return;
  }
  const float* in; unsigned short* out; int R, C, bx, by;
  if (id < 7168) {
    const int t2 = id - 4096;
    in = Wqkv; out = WQT; R = HDIM; C = 3 * HDIM;
    bx = (t2 % 96) * 32; by = (t2 / 96) * 32;
  } else {
    const int t3 = id - 7168;
    in = Wout; out = WOT; R = HDIM; C = HDIM;
    bx = (t3 & 31) * 32; by = (t3 >> 5) * 32;
  }
  const int tx = threadIdx.x & 31, ty = threadIdx.x >> 5;  // (32,8)
#pragma unroll
  for (int j = 0; j < 32; j += 8)
    tile[ty + j][tx] = in[(size_t)(by + ty + j) * C + bx + tx];
  __syncthreads();
#pragma unroll
  for (int j = 0; j < 32; j += 8)
    out[(size_t)(bx + ty + j) * R + by + tx] = f2bf(tile[tx][ty + j]);
}

// ---------------- GEMM1: C(4096x3072) = Aeff(4096x1024) @ Wt(3072x1024)^T ----------------
// R0/R4 serial 2-barrier structure, DEFAULT block mapping (R5 XCD-patch swizzle
// regressed 45.7->53.2us; reverted). R1-R3: all schedule/occupancy tweaks
// regressed. NEW R6: chunk-XOR LDS swizzle (T2 adapted to global_load_lds's
// linear-dest constraint): physical 16B-chunk p holds semantic chunk
// s = p ^ ((p>>3)&7) (involution). Staging threads pre-permute the GLOBAL
// source (m173 pattern, same 64B segments -> coalescing preserved); ds_reads
// apply the same XOR. Kills the 8-way bank-start collision of 64B-row
// fragment reads (SQ_LDS_BANK_CONFLICT 3.15M/dispatch, 4cy per b128).
// V blocks compute C^T via operand swap so the V^T store is 32B s-runs.
__global__ __launch_bounds__(256) void gemm_qkv_kernel(
    const unsigned short* __restrict__ XP, const unsigned short* __restrict__ X,
    const unsigned short* __restrict__ Wt,
    unsigned short* __restrict__ Qb, unsigned short* __restrict__ Kb,
    unsigned short* __restrict__ VTb) {
  __shared__ unsigned short As[2][128 * 32];
  __shared__ unsigned short Bs[2][128 * 32];
  const int m0 = blockIdx.x * 128;
  const int n0 = blockIdx.y * 128;
  const bool isV = (n0 >= 2 * HDIM);
  const unsigned short* A = isV ? X : XP;
  const int t = threadIdx.x;
  const int lane = t & 63, w = t >> 6;
  const int wm = (w >> 1) * 64, wn = (w & 1) * 64;
  const int quad = lane >> 4, l15 = lane & 15;

  v4f acc[4][4] = {};

  // staging source permutation: thread t (writing physical chunk t) fetches
  // semantic chunk s0 = t ^ ((t>>3)&7)  -> row s0>>2, col-quad s0&3
  const int s0c = t ^ ((t >> 3) & 7);
  const int rowA = s0c >> 2;          // 0..63
  const int colA = (s0c & 3) * 8;
  const unsigned short* gA = A + (size_t)(m0 + rowA) * HDIM + colA;
  const unsigned short* gB = Wt + (size_t)(n0 + rowA) * HDIM + colA;

  // ds_read physical-chunk bases (elements): fragment (row=wm/wn+i*16+l15, quad)
  // -> semantic s = 4*row+quad; physical p = s ^ ((s>>3)&7) = (base^v) + i*64
  const int baseA = 4 * (wm + l15) + quad;
  const int pA0 = (baseA ^ ((baseA >> 3) & 7)) * 8;   // element offset, +i*512
  const int baseB = 4 * (wn + l15) + quad;
  const int pB0 = (baseB ^ ((baseB >> 3) & 7)) * 8;

  for (int k0 = 0; k0 < HDIM; k0 += 64) {
    __syncthreads();
#pragma unroll
    for (int kh = 0; kh < 2; kh++) {
      async16(gA + k0 + kh * 32, &As[kh][t * 8]);
      async16(gA + 64 * HDIM + k0 + kh * 32, &As[kh][2048 + t * 8]);
      async16(gB + k0 + kh * 32, &Bs[kh][t * 8]);
      async16(gB + 64 * HDIM + k0 + kh * 32, &Bs[kh][2048 + t * 8]);
    }
    __syncthreads();
#pragma unroll
    for (int kh = 0; kh < 2; kh++) {
      v8bf a[4], b[4];
#pragma unroll
      for (int i = 0; i < 4; i++)
        a[i] = *(const v8bf*)&As[kh][pA0 + i * 512];
#pragma unroll
      for (int i = 0; i < 4; i++)
        b[i] = *(const v8bf*)&Bs[kh][pB0 + i * 512];
      if (isV) {
#pragma unroll
        for (int i = 0; i < 4; i++)
#pragma unroll
          for (int j = 0; j < 4; j++)
            acc[i][j] = MFMA16(b[j], a[i], acc[i][j]);   // C^T
      } else {
#pragma unroll
        for (int i = 0; i < 4; i++)
#pragma unroll
          for (int j = 0; j < 4; j++)
            acc[i][j] = MFMA16(a[i], b[j], acc[i][j]);
      }
    }
  }

  const int b_ = m0 >> 11;
  const int s0 = m0 & (SEQ - 1);

  if (isV) {
    // acc[i][j] = C^T: D[row=quad*4+r -> Wt col (d)][col=l15 -> token (s)]
#pragma unroll
    for (int i = 0; i < 4; i++) {
#pragma unroll
      for (int j = 0; j < 4; j++) {
        const int s_ = s0 + wm + i * 16 + l15;
#pragma unroll
        for (int r = 0; r < 4; r++) {
          const int c2 = (n0 - 2 * HDIM) + wn + j * 16 + quad * 4 + r;
          const int h = c2 >> 6, d = c2 & 63;
          VTb[((size_t)(((b_ << 4) | h) * HS + d)) * SEQ + s_] = f2bf(acc[i][j][r]);
        }
      }
    }
  } else {
    // Q/K[(b,h,s), d]: scatter, 16 consecutive lanes form 32B d-runs
    const float scale = (n0 < HDIM) ? QSCALE : 1.0f;
    unsigned short* dst = (n0 < HDIM) ? Qb : Kb;
#pragma unroll
    for (int i = 0; i < 4; i++) {
#pragma unroll
      for (int j = 0; j < 4; j++) {
#pragma unroll
        for (int r = 0; r < 4; r++) {
          const int s_ = s0 + wm + i * 16 + quad * 4 + r;
          const int c2 = (n0 & (HDIM - 1)) + wn + j * 16 + l15;
          const int h = c2 >> 6, d = c2 & 63;
          dst[((size_t)(((b_ << 4) | h) * SEQ + s_)) * HS + d] =
              f2bf(acc[i][j][r] * scale);
        }
      }
    }
  }
}

// ---------------- flash attention, complementary-pair balanced + Qs/Ps union --------
// Block (bh, p): q-tiles qlo=p and qhi=31-p (64 rows each), one K/V stream over
// chunks 0..qhi; exactly 33 chunk-tiles per block. Qs (dead after fragment
// load) is overlaid by per-wave Ps => LDS 36,864 B => 4 blocks/CU at 88 VGPR.
// NOTE: launch_bounds min-waves MUST stay 2 — forcing 4 caps VGPR at 64 and
// spills ~60MB to scratch (R10: dur 46->109us, WRITE 8->68MB).
// LP=72 (144B rows) already spreads fragment reads across banks (2-way, free).
__global__ __launch_bounds__(256, 2) void attn_pair_kernel(
    const unsigned short* __restrict__ Qp, const unsigned short* __restrict__ Kp,
    const unsigned short* __restrict__ Vp, unsigned short* __restrict__ ATTN) {
  __shared__ unsigned short SM[18432];       // 36,864 B
  unsigned short* Ks = SM;                   // 64*LP
  unsigned short* Vs = SM + 4608;            // 64*LP (V^T chunk: [d][key])
  unsigned short* QPs = SM + 9216;           // 128*LP union: Qs (init) / Ps (loop)

  const int bh = blockIdx.x;
  const int p  = blockIdx.y;        // 0..15
  const int b_ = bh >> 4, h = bh & 15;
  const int qlo = p, qhi = 31 - p;
  const int q0lo = qlo * 64, q0hi = qhi * 64;
  const int t = threadIdx.x;
  const int lane = t & 63, w = t >> 6;
  const int quad = lane >> 4, l15 = lane & 15;

  const unsigned short* Qg = Qp + (size_t)bh * SEQ * HS;
  const unsigned short* Kg = Kp + (size_t)bh * SEQ * HS;
  const unsigned short* Vg = Vp + (size_t)bh * HS * SEQ;

  const int sr = t >> 3, scol = (t & 7) * 8;
  *(uint4*)&QPs[sr * LP + scol] = *(const uint4*)(Qg + (size_t)(q0lo + sr) * HS + scol);
  *(uint4*)&QPs[(sr + 32) * LP + scol] =
      *(const uint4*)(Qg + (size_t)(q0lo + sr + 32) * HS + scol);
  *(uint4*)&QPs[(sr + 64) * LP + scol] =
      *(const uint4*)(Qg + (size_t)(q0hi + sr) * HS + scol);
  *(uint4*)&QPs[(sr + 96) * LP + scol] =
      *(const uint4*)(Qg + (size_t)(q0hi + sr + 32) * HS + scol);
  __syncthreads();

  // Q rows as B-operand fragments: [tile][khalf]. After these ds_reads drain
  // (at the first in-loop __syncthreads), QPs is reused as per-wave Ps.
  v8bf bq[2][2];
#pragma unroll
  for (int tl = 0; tl < 2; tl++)
#pragma unroll
    for (int kh = 0; kh < 2; kh++)
      bq[tl][kh] = *(const v8bf*)&QPs[(tl * 64 + w * 16 + l15) * LP + kh * 32 + quad * 8];

  unsigned short* Ps_w = QPs + w * 32 * LP;  // 32 rows/wave: 0-15 lo, 16-31 hi

  v8bf ones;
#pragma unroll
  for (int j = 0; j < 8; j++) ones[j] = (__bf16)1.0f;

  v4f o[2][4] = {};
  v4f lacc[2] = {};

  // register prefetch of chunk 0
  uint4 kr0, kr1, vr0, vr1;
  kr0 = *(const uint4*)(Kg + (size_t)sr * HS + scol);
  kr1 = *(const uint4*)(Kg + (size_t)(sr + 32) * HS + scol);
  vr0 = *(const uint4*)(Vg + (size_t)sr * SEQ + scol);
  vr1 = *(const uint4*)(Vg + (size_t)(sr + 32) * SEQ + scol);

  const int qrow_hi = q0hi + w * 16 + l15;  // lane's q-row in S^T
  const int qrow_lo = q0lo + w * 16 + l15;

  for (int cI = 0; cI <= qhi; cI++) {
    const int kc = cI * 64;
    __syncthreads();  // previous chunk's K/V (and init bq) LDS reads done
    *(uint4*)&Ks[sr * LP + scol] = kr0;
    *(uint4*)&Ks[(sr + 32) * LP + scol] = kr1;
    *(uint4*)&Vs[sr * LP + scol] = vr0;
    *(uint4*)&Vs[(sr + 32) * LP + scol] = vr1;
    if (cI < qhi) {  // prefetch next chunk while computing this one
      const int kn = kc + 64;
      kr0 = *(const uint4*)(Kg + (size_t)(kn + sr) * HS + scol);
      kr1 = *(const uint4*)(Kg + (size_t)(kn + sr + 32) * HS + scol);
      vr0 = *(const uint4*)(Vg + (size_t)sr * SEQ + kn + scol);
      vr1 = *(const uint4*)(Vg + (size_t)(sr + 32) * SEQ + kn + scol);
    }
    __syncthreads();

    // K fragments (A-operand), shared across both tiles
    v8bf kf0[4], kf1[4];
#pragma unroll
    for (int ni = 0; ni < 4; ni++) {
      kf0[ni] = *(const v8bf*)&Ks[(ni * 16 + l15) * LP + quad * 8];
      kf1[ni] = *(const v8bf*)&Ks[(ni * 16 + l15) * LP + 32 + quad * 8];
    }

    const bool doLo = (cI <= qlo);

    // ---- hi tile: S^T = K Q^T, D[key=quad*4+r][qrow=l15] ----
    {
      v4f sc[4] = {};
#pragma unroll
      for (int ni = 0; ni < 4; ni++) {
        sc[ni] = MFMA16(kf0[ni], bq[1][0], sc[ni]);
        sc[ni] = MFMA16(kf1[ni], bq[1][1], sc[ni]);
      }
      if (cI == qhi) {
#pragma unroll
        for (int ni = 0; ni < 4; ni++) {
          const int key = kc + ni * 16 + quad * 4;
#pragma unroll
          for (int r = 0; r < 4; r++)
            if (key + r > qrow_hi) sc[ni][r] = -1e30f;
        }
      }
#pragma unroll
      for (int ni = 0; ni < 4; ni++) {
        const float p0 = exp2f(sc[ni][0]), p1 = exp2f(sc[ni][1]);
        const float p2 = exp2f(sc[ni][2]), p3 = exp2f(sc[ni][3]);
        uint2 pk;
        pk.x = __builtin_amdgcn_perm(__float_as_uint(p1), __float_as_uint(p0), 0x07060302u);
        pk.y = __builtin_amdgcn_perm(__float_as_uint(p3), __float_as_uint(p2), 0x07060302u);
        *(uint2*)&Ps_w[(16 + l15) * LP + ni * 16 + quad * 4] = pk;
      }
    }
    // ---- lo tile (wave-uniform skip once cI > qlo) ----
    if (doLo) {
      v4f sc[4] = {};
#pragma unroll
      for (int ni = 0; ni < 4; ni++) {
        sc[ni] = MFMA16(kf0[ni], bq[0][0], sc[ni]);
        sc[ni] = MFMA16(kf1[ni], bq[0][1], sc[ni]);
      }
      if (cI == qlo) {
#pragma unroll
        for (int ni = 0; ni < 4; ni++) {
          const int key = kc + ni * 16 + quad * 4;
#pragma unroll
          for (int r = 0; r < 4; r++)
            if (key + r > qrow_lo) sc[ni][r] = -1e30f;
        }
      }
#pragma unroll
      for (int ni = 0; ni < 4; ni++) {
        const float p0 = exp2f(sc[ni][0]), p1 = exp2f(sc[ni][1]);
        const float p2 = exp2f(sc[ni][2]), p3 = exp2f(sc[ni][3]);
        uint2 pk;
        pk.x = __builtin_amdgcn_perm(__float_as_uint(p1), __float_as_uint(p0), 0x07060302u);
        pk.y = __builtin_amdgcn_perm(__float_as_uint(p3), __float_as_uint(p2), 0x07060302u);
        *(uint2*)&Ps_w[l15 * LP + ni * 16 + quad * 4] = pk;
      }
    }

    // ---- O += P @ V, l += P @ 1; V fragments shared across tiles ----
#pragma unroll
    for (int ki = 0; ki < 2; ki++) {
      v8bf pahi = *(const v8bf*)&Ps_w[(16 + l15) * LP + ki * 32 + quad * 8];
      lacc[1] = MFMA16(pahi, ones, lacc[1]);
      v8bf palo;
      if (doLo) {
        palo = *(const v8bf*)&Ps_w[l15 * LP + ki * 32 + quad * 8];
        lacc[0] = MFMA16(palo, ones, lacc[0]);
      }
#pragma unroll
      for (int ni = 0; ni < 4; ni++) {
        v8bf vb = *(const v8bf*)&Vs[(ni * 16 + l15) * LP + ki * 32 + quad * 8];
        o[1][ni] = MFMA16(pahi, vb, o[1][ni]);
        if (doLo) o[0][ni] = MFMA16(palo, vb, o[0][ni]);
      }
    }
  }

  // epilogue: normalize and store both tiles (C-layout rows = quad*4+r)
#pragma unroll
  for (int tl = 0; tl < 2; tl++) {
    const int q0 = tl ? q0hi : q0lo;
    const int row_base = q0 + w * 16 + quad * 4;
    float invl[4];
#pragma unroll
    for (int r = 0; r < 4; r++) invl[r] = 1.0f / lacc[tl][r];
#pragma unroll
    for (int ni = 0; ni < 4; ni++)
#pragma unroll
      for (int r = 0; r < 4; r++) {
        const int tr = b_ * SEQ + row_base + r;
        ATTN[(size_t)tr * HDIM + h * HS + ni * 16 + l15] = f2bf(o[tl][ni][r] * invl[r]);
      }
  }
}

// ---------------- GEMM2: out(4096x1024) = ATTN @ WOT^T, fp32 out ----------------
// 128x64 tiles -> 512 blocks (2/CU); 3-deep counted-vmcnt pipeline (neutral vs
// R0's simple loop per R4 totals; kept unchanged for attribution).
__global__ __launch_bounds__(256) void gemm_out_kernel(
    const unsigned short* __restrict__ Ab, const unsigned short* __restrict__ Wt,
    float* __restrict__ out) {
  __shared__ unsigned short As[3][128 * 32];
  __shared__ unsigned short Bs[3][64 * 32];
  const int m0 = blockIdx.x * 128;
  const int n0 = blockIdx.y * 64;
  const int t = threadIdx.x;
  const int lane = t & 63, w = t >> 6;
  const int wm = w * 32;
  const int quad = lane >> 4, l15 = lane & 15;

  v4f acc[2][4] = {};

  const int rowA = t >> 2;
  const int colA = (t & 3) * 8;
  const unsigned short* gA = Ab + (size_t)(m0 + rowA) * HDIM + colA;
  const unsigned short* gB = Wt + (size_t)(n0 + rowA) * HDIM + colA;

  auto issue = [&](int k0, int buf) {
    async16(gA + k0, &As[buf][t * 8]);
    async16(gA + 64 * HDIM + k0, &As[buf][2048 + t * 8]);
    async16(gB + k0, &Bs[buf][t * 8]);   // rowA is always <64: all threads load B
  };
  auto compute = [&](int buf) {
    v8bf a[2], b[4];
#pragma unroll
    for (int i = 0; i < 2; i++)
      a[i] = *(const v8bf*)&As[buf][(wm + i * 16 + l15) * 32 + quad * 8];
#pragma unroll
    for (int j = 0; j < 4; j++)
      b[j] = *(const v8bf*)&Bs[buf][(j * 16 + l15) * 32 + quad * 8];
#pragma unroll
    for (int i = 0; i < 2; i++)
#pragma unroll
      for (int j = 0; j < 4; j++)
        acc[i][j] = MFMA16(a[i], b[j], acc[i][j]);
  };

  issue(0, 0);
  issue(32, 1);
  asm volatile("s_waitcnt vmcnt(3)" ::: "memory");
  __builtin_amdgcn_s_barrier();
  asm volatile("" ::: "memory");

  int cur = 0;
#pragma unroll 3
  for (int kt = 0; kt < 30; ++kt) {
    int ib = cur + 2; if (ib >= 3) ib -= 3;
    issue((kt + 2) * 32, ib);
    compute(cur);
    asm volatile("s_waitcnt vmcnt(3)" ::: "memory");
    __builtin_amdgcn_s_barrier();
    asm volatile("" ::: "memory");
    if (++cur == 3) cur = 0;
  }
  compute(cur);
  asm volatile("s_waitcnt vmcnt(0)" ::: "memory");
  __builtin_amdgcn_s_barrier();
  asm volatile("" ::: "memory");
  if (++cur == 3) cur = 0;
  compute(cur);

#pragma unroll
  for (int i = 0; i < 2; i++) {
#pragma unroll
    for (int j = 0; j < 4; j++) {
#pragma unroll
      for (int r = 0; r < 4; r++) {
        const int tr = m0 + wm + i * 16 + quad * 4 + r;
        const int c = n0 + j * 16 + l15;
        out[(size_t)tr * HDIM + c] = acc[i][j][r];
      }
    }
  }
}

extern "C" void kernel_launch(void* const* d_in, const int* in_sizes, int n_in,
                              void* d_out, int out_size, void* d_ws, size_t ws_size,
                              hipStream_t stream) {
  (void)in_sizes; (void)n_in; (void)out_size; (void)ws_size;
  const float* x    = (const float*)d_in[0];
  const float* pos  = (const float*)d_in[1];
  const float* Wqkv = (const float*)d_in[2];
  const float* Wout = (const float*)d_in[3];
  float* out = (float*)d_out;

  char* ws = (char*)d_ws;
  unsigned short* XP   = (unsigned short*)(ws);
  unsigned short* X    = (unsigned short*)(ws + ((size_t)8  << 20));
  unsigned short* WQT  = (unsigned short*)(ws + ((size_t)16 << 20));
  unsigned short* WOT  = (unsigned short*)(ws + ((size_t)22 << 20));
  unsigned short* Qb   = (unsigned short*)(ws + ((size_t)24 << 20));
  unsigned short* Kb   = (unsigned short*)(ws + ((size_t)32 << 20));
  unsigned short* VTb  = (unsigned short*)(ws + ((size_t)40 << 20));
  unsigned short* ATTN = (unsigned short*)(ws + ((size_t)48 << 20));

  prep_all_kernel<<<8192, 256, 0, stream>>>(x, pos, Wqkv, Wout, X, XP, WQT, WOT);

  dim3 g1(TOKENS / 128, 3 * HDIM / 128);
  gemm_qkv_kernel<<<g1, 256, 0, stream>>>(XP, X, WQT, Qb, Kb, VTb);

  dim3 g2(2 * NHEADS, 16);
  attn_pair_kernel<<<g2, 256, 0, stream>>>(Qb, Kb, VTb, ATTN);

  dim3 g3(TOKENS / 128, HDIM / 64);
  gemm_out_kernel<<<g3, 256, 0, stream>>>(ATTN, WOT, out);
}

// Round 7
// 181.725 us; speedup vs baseline: 1.7077x; 1.0157x over previous
//
#include <hip/hip_runtime.h>

#define SEQ     2048
#define HDIM    1024
#define TOKENS  4096   // B*SEQ
#define NHEADS  16
#define HS      64
#define LP      72     // padded LDS row stride for Q/P region only

typedef __bf16 v8bf __attribute__((ext_vector_type(8)));
typedef float  v4f  __attribute__((ext_vector_type(4)));

#define MFMA16(a, b, c) __builtin_amdgcn_mfma_f32_16x16x32_bf16((a), (b), (c), 0, 0, 0)

// scores arrive in log2 units: 1/sqrt(64) * log2(e) folded into Q pre-scale
#define QSCALE (0.125f * 1.44269504088896f)

__device__ __forceinline__ unsigned short f2bf(float f) {
  unsigned int u = __float_as_uint(f);
  u += 0x7FFFu + ((u >> 16) & 1u);   // RNE
  return (unsigned short)(u >> 16);
}

__device__ __forceinline__ void async16(const void* g, void* l) {
  __builtin_amdgcn_global_load_lds(
      (const __attribute__((address_space(1))) void*)g,
      (__attribute__((address_space(3))) void*)l, 16, 0, 0);
}

// ---------------- fused prep: x casts + both weight transposes ----------------
__global__ __launch_bounds__(256) void prep_all_kernel(
    const float* __restrict__ x, const float* __restrict__ pos,
    const float* __restrict__ Wqkv, const float* __restrict__ Wout,
    unsigned short* __restrict__ X, unsigned short* __restrict__ XP,
    unsigned short* __restrict__ WQT, unsigned short* __restrict__ WOT) {
  __shared__ float tile[32][33];
  const int id = blockIdx.x;
  if (id < 4096) {
    const int i = (id * 256 + threadIdx.x) * 4;
    float4 xv = *(const float4*)(x + i);
    float4 pv = *(const float4*)(pos + (i & (SEQ * HDIM - 1)));
    ushort4 a, b;
    a.x = f2bf(xv.x); a.y = f2bf(xv.y); a.z = f2bf(xv.z); a.w = f2bf(xv.w);
    b.x = f2bf(xv.x + pv.x); b.y = f2bf(xv.y + pv.y);
    b.z = f2bf(xv.z + pv.z); b.w = f2bf(xv.w + pv.w);
    *(ushort4*)(X + i) = a;
    *(ushort4*)(XP + i) = b;
    return;
  }
  const float* in; unsigned short* out; int R, C, bx, by;
  if (id < 7168) {
    const int t2 = id - 4096;
    in = Wqkv; out = WQT; R = HDIM; C = 3 * HDIM;
    bx = (t2 % 96) * 32; by = (t2 / 96) * 32;
  } else {
    const int t3 = id - 7168;
    in = Wout; out = WOT; R = HDIM; C = HDIM;
    bx = (t3 & 31) * 32; by = (t3 >> 5) * 32;
  }
  const int tx = threadIdx.x & 31, ty = threadIdx.x >> 5;  // (32,8)
#pragma unroll
  for (int j = 0; j < 32; j += 8)
    tile[ty + j][tx] = in[(size_t)(by + ty + j) * C + bx + tx];
  __syncthreads();
#pragma unroll
  for (int j = 0; j < 32; j += 8)
    out[(size_t)(bx + ty + j) * R + by + tx] = f2bf(tile[tx][ty + j]);
}

// ---------------- GEMM1: C(4096x3072) = Aeff(4096x1024) @ Wt(3072x1024)^T ----------------
// R0 serial 2-barrier structure + R6 chunk-XOR LDS swizzle (CONFIRMED win:
// gemm_qkv dropped below attn in the top-5). Physical 16B-chunk p holds
// semantic chunk s = p ^ ((p>>3)&7); staging pre-permutes the GLOBAL source
// (m173 pattern); ds_reads apply the same XOR.
// V blocks compute C^T via operand swap so the V^T store is 32B s-runs.
__global__ __launch_bounds__(256) void gemm_qkv_kernel(
    const unsigned short* __restrict__ XP, const unsigned short* __restrict__ X,
    const unsigned short* __restrict__ Wt,
    unsigned short* __restrict__ Qb, unsigned short* __restrict__ Kb,
    unsigned short* __restrict__ VTb) {
  __shared__ unsigned short As[2][128 * 32];
  __shared__ unsigned short Bs[2][128 * 32];
  const int m0 = blockIdx.x * 128;
  const int n0 = blockIdx.y * 128;
  const bool isV = (n0 >= 2 * HDIM);
  const unsigned short* A = isV ? X : XP;
  const int t = threadIdx.x;
  const int lane = t & 63, w = t >> 6;
  const int wm = (w >> 1) * 64, wn = (w & 1) * 64;
  const int quad = lane >> 4, l15 = lane & 15;

  v4f acc[4][4] = {};

  const int s0c = t ^ ((t >> 3) & 7);
  const int rowA = s0c >> 2;          // 0..63
  const int colA = (s0c & 3) * 8;
  const unsigned short* gA = A + (size_t)(m0 + rowA) * HDIM + colA;
  const unsigned short* gB = Wt + (size_t)(n0 + rowA) * HDIM + colA;

  const int baseA = 4 * (wm + l15) + quad;
  const int pA0 = (baseA ^ ((baseA >> 3) & 7)) * 8;   // element offset, +i*512
  const int baseB = 4 * (wn + l15) + quad;
  const int pB0 = (baseB ^ ((baseB >> 3) & 7)) * 8;

  for (int k0 = 0; k0 < HDIM; k0 += 64) {
    __syncthreads();
#pragma unroll
    for (int kh = 0; kh < 2; kh++) {
      async16(gA + k0 + kh * 32, &As[kh][t * 8]);
      async16(gA + 64 * HDIM + k0 + kh * 32, &As[kh][2048 + t * 8]);
      async16(gB + k0 + kh * 32, &Bs[kh][t * 8]);
      async16(gB + 64 * HDIM + k0 + kh * 32, &Bs[kh][2048 + t * 8]);
    }
    __syncthreads();
#pragma unroll
    for (int kh = 0; kh < 2; kh++) {
      v8bf a[4], b[4];
#pragma unroll
      for (int i = 0; i < 4; i++)
        a[i] = *(const v8bf*)&As[kh][pA0 + i * 512];
#pragma unroll
      for (int i = 0; i < 4; i++)
        b[i] = *(const v8bf*)&Bs[kh][pB0 + i * 512];
      if (isV) {
#pragma unroll
        for (int i = 0; i < 4; i++)
#pragma unroll
          for (int j = 0; j < 4; j++)
            acc[i][j] = MFMA16(b[j], a[i], acc[i][j]);   // C^T
      } else {
#pragma unroll
        for (int i = 0; i < 4; i++)
#pragma unroll
          for (int j = 0; j < 4; j++)
            acc[i][j] = MFMA16(a[i], b[j], acc[i][j]);
      }
    }
  }

  const int b_ = m0 >> 11;
  const int s0 = m0 & (SEQ - 1);

  if (isV) {
    // acc[i][j] = C^T: D[row=quad*4+r -> Wt col (d)][col=l15 -> token (s)]
#pragma unroll
    for (int i = 0; i < 4; i++) {
#pragma unroll
      for (int j = 0; j < 4; j++) {
        const int s_ = s0 + wm + i * 16 + l15;
#pragma unroll
        for (int r = 0; r < 4; r++) {
          const int c2 = (n0 - 2 * HDIM) + wn + j * 16 + quad * 4 + r;
          const int h = c2 >> 6, d = c2 & 63;
          VTb[((size_t)(((b_ << 4) | h) * HS + d)) * SEQ + s_] = f2bf(acc[i][j][r]);
        }
      }
    }
  } else {
    // Q/K[(b,h,s), d]: scatter, 16 consecutive lanes form 32B d-runs
    const float scale = (n0 < HDIM) ? QSCALE : 1.0f;
    unsigned short* dst = (n0 < HDIM) ? Qb : Kb;
#pragma unroll
    for (int i = 0; i < 4; i++) {
#pragma unroll
      for (int j = 0; j < 4; j++) {
#pragma unroll
        for (int r = 0; r < 4; r++) {
          const int s_ = s0 + wm + i * 16 + quad * 4 + r;
          const int c2 = (n0 & (HDIM - 1)) + wn + j * 16 + l15;
          const int h = c2 >> 6, d = c2 & 63;
          dst[((size_t)(((b_ << 4) | h) * SEQ + s_)) * HS + d] =
              f2bf(acc[i][j][r] * scale);
        }
      }
    }
  }
}

// ---------------- flash attention, complementary-pair balanced + Qs/Ps union --------
// Block (bh, p): q-tiles qlo=p and qhi=31-p (64 rows each), K/V stream over
// chunks 0..qhi; 33 chunk-tiles per block. R7: Ks/Vs switch from LP=72-padded
// rows to LINEAR [64][64] + chunk-XOR swizzle (R6-proven math). LP=72 made
// fragment reads 2-way but staging WRITES 8-way (bank = 4*(sr+c) mod 32, 8
// lanes per 4-bank group) — the bulk of attn's 4.87M conflicts. Swizzle:
// physical 16B-chunk p = s ^ ((s>>3)&7); reg-staged write goes to p (regs
// unchanged, no global-side permute needed); reads use row*64 +
// ((c ^ (l15&7))*8), c = kh*4+quad (K) / ki*4+quad (V). Writes AND reads
// land 2 lanes per 4-bank group = conflict-free. QPs/Ps keeps LP=72.
// LDS 34,816B. launch_bounds min-waves MUST stay 2 (VGPR cap spills at 4).
__global__ __launch_bounds__(256, 2) void attn_pair_kernel(
    const unsigned short* __restrict__ Qp, const unsigned short* __restrict__ Kp,
    const unsigned short* __restrict__ Vp, unsigned short* __restrict__ ATTN) {
  __shared__ unsigned short SM[17408];       // 34,816 B
  unsigned short* Ks = SM;                   // [64][64] linear, XOR-swizzled
  unsigned short* Vs = SM + 4096;            // [64][64] linear (V^T: [d][key])
  unsigned short* QPs = SM + 8192;           // 128*LP union: Qs (init) / Ps (loop)

  const int bh = blockIdx.x;
  const int p  = blockIdx.y;        // 0..15
  const int b_ = bh >> 4, h = bh & 15;
  const int qlo = p, qhi = 31 - p;
  const int q0lo = qlo * 64, q0hi = qhi * 64;
  const int t = threadIdx.x;
  const int lane = t & 63, w = t >> 6;
  const int quad = lane >> 4, l15 = lane & 15;

  const unsigned short* Qg = Qp + (size_t)bh * SEQ * HS;
  const unsigned short* Kg = Kp + (size_t)bh * SEQ * HS;
  const unsigned short* Vg = Vp + (size_t)bh * HS * SEQ;

  const int sr = t >> 3, scol = (t & 7) * 8;
  // K/V staging dest: physical chunk for semantic chunk t (and t+256)
  const int pst = (t ^ ((t >> 3) & 7)) * 8;
  // K/V fragment read column XORs: c=quad (kh/ki=0), c=quad+4 (kh/ki=1)
  const int xq0 = (quad ^ (l15 & 7)) * 8;
  const int xq1 = ((quad + 4) ^ (l15 & 7)) * 8;

  *(uint4*)&QPs[sr * LP + scol] = *(const uint4*)(Qg + (size_t)(q0lo + sr) * HS + scol);
  *(uint4*)&QPs[(sr + 32) * LP + scol] =
      *(const uint4*)(Qg + (size_t)(q0lo + sr + 32) * HS + scol);
  *(uint4*)&QPs[(sr + 64) * LP + scol] =
      *(const uint4*)(Qg + (size_t)(q0hi + sr) * HS + scol);
  *(uint4*)&QPs[(sr + 96) * LP + scol] =
      *(const uint4*)(Qg + (size_t)(q0hi + sr + 32) * HS + scol);
  __syncthreads();

  // Q rows as B-operand fragments: [tile][khalf]. After these ds_reads drain
  // (at the first in-loop __syncthreads), QPs is reused as per-wave Ps.
  v8bf bq[2][2];
#pragma unroll
  for (int tl = 0; tl < 2; tl++)
#pragma unroll
    for (int kh = 0; kh < 2; kh++)
      bq[tl][kh] = *(const v8bf*)&QPs[(tl * 64 + w * 16 + l15) * LP + kh * 32 + quad * 8];

  unsigned short* Ps_w = QPs + w * 32 * LP;  // 32 rows/wave: 0-15 lo, 16-31 hi

  v8bf ones;
#pragma unroll
  for (int j = 0; j < 8; j++) ones[j] = (__bf16)1.0f;

  v4f o[2][4] = {};
  v4f lacc[2] = {};

  // register prefetch of chunk 0
  uint4 kr0, kr1, vr0, vr1;
  kr0 = *(const uint4*)(Kg + (size_t)sr * HS + scol);
  kr1 = *(const uint4*)(Kg + (size_t)(sr + 32) * HS + scol);
  vr0 = *(const uint4*)(Vg + (size_t)sr * SEQ + scol);
  vr1 = *(const uint4*)(Vg + (size_t)(sr + 32) * SEQ + scol);

  const int qrow_hi = q0hi + w * 16 + l15;  // lane's q-row in S^T
  const int qrow_lo = q0lo + w * 16 + l15;

  for (int cI = 0; cI <= qhi; cI++) {
    const int kc = cI * 64;
    __syncthreads();  // previous chunk's K/V (and init bq) LDS reads done
    *(uint4*)&Ks[pst] = kr0;
    *(uint4*)&Ks[pst + 2048] = kr1;
    *(uint4*)&Vs[pst] = vr0;
    *(uint4*)&Vs[pst + 2048] = vr1;
    if (cI < qhi) {  // prefetch next chunk while computing this one
      const int kn = kc + 64;
      kr0 = *(const uint4*)(Kg + (size_t)(kn + sr) * HS + scol);
      kr1 = *(const uint4*)(Kg + (size_t)(kn + sr + 32) * HS + scol);
      vr0 = *(const uint4*)(Vg + (size_t)sr * SEQ + kn + scol);
      vr1 = *(const uint4*)(Vg + (size_t)(sr + 32) * SEQ + kn + scol);
    }
    __syncthreads();

    // K fragments (A-operand), shared across both tiles
    v8bf kf0[4], kf1[4];
#pragma unroll
    for (int ni = 0; ni < 4; ni++) {
      kf0[ni] = *(const v8bf*)&Ks[(ni * 16 + l15) * 64 + xq0];
      kf1[ni] = *(const v8bf*)&Ks[(ni * 16 + l15) * 64 + xq1];
    }

    const bool doLo = (cI <= qlo);

    // ---- hi tile: S^T = K Q^T, D[key=quad*4+r][qrow=l15] ----
    {
      v4f sc[4] = {};
#pragma unroll
      for (int ni = 0; ni < 4; ni++) {
        sc[ni] = MFMA16(kf0[ni], bq[1][0], sc[ni]);
        sc[ni] = MFMA16(kf1[ni], bq[1][1], sc[ni]);
      }
      if (cI == qhi) {
#pragma unroll
        for (int ni = 0; ni < 4; ni++) {
          const int key = kc + ni * 16 + quad * 4;
#pragma unroll
          for (int r = 0; r < 4; r++)
            if (key + r > qrow_hi) sc[ni][r] = -1e30f;
        }
      }
#pragma unroll
      for (int ni = 0; ni < 4; ni++) {
        const float p0 = exp2f(sc[ni][0]), p1 = exp2f(sc[ni][1]);
        const float p2 = exp2f(sc[ni][2]), p3 = exp2f(sc[ni][3]);
        uint2 pk;
        pk.x = __builtin_amdgcn_perm(__float_as_uint(p1), __float_as_uint(p0), 0x07060302u);
        pk.y = __builtin_amdgcn_perm(__float_as_uint(p3), __float_as_uint(p2), 0x07060302u);
        *(uint2*)&Ps_w[(16 + l15) * LP + ni * 16 + quad * 4] = pk;
      }
    }
    // ---- lo tile (wave-uniform skip once cI > qlo) ----
    if (doLo) {
      v4f sc[4] = {};
#pragma unroll
      for (int ni = 0; ni < 4; ni++) {
        sc[ni] = MFMA16(kf0[ni], bq[0][0], sc[ni]);
        sc[ni] = MFMA16(kf1[ni], bq[0][1], sc[ni]);
      }
      if (cI == qlo) {
#pragma unroll
        for (int ni = 0; ni < 4; ni++) {
          const int key = kc + ni * 16 + quad * 4;
#pragma unroll
          for (int r = 0; r < 4; r++)
            if (key + r > qrow_lo) sc[ni][r] = -1e30f;
        }
      }
#pragma unroll
      for (int ni = 0; ni < 4; ni++) {
        const float p0 = exp2f(sc[ni][0]), p1 = exp2f(sc[ni][1]);
        const float p2 = exp2f(sc[ni][2]), p3 = exp2f(sc[ni][3]);
        uint2 pk;
        pk.x = __builtin_amdgcn_perm(__float_as_uint(p1), __float_as_uint(p0), 0x07060302u);
        pk.y = __builtin_amdgcn_perm(__float_as_uint(p3), __float_as_uint(p2), 0x07060302u);
        *(uint2*)&Ps_w[l15 * LP + ni * 16 + quad * 4] = pk;
      }
    }

    // ---- O += P @ V, l += P @ 1; V fragments shared across tiles ----
#pragma unroll
    for (int ki = 0; ki < 2; ki++) {
      v8bf pahi = *(const v8bf*)&Ps_w[(16 + l15) * LP + ki * 32 + quad * 8];
      lacc[1] = MFMA16(pahi, ones, lacc[1]);
      v8bf palo;
      if (doLo) {
        palo = *(const v8bf*)&Ps_w[l15 * LP + ki * 32 + quad * 8];
        lacc[0] = MFMA16(palo, ones, lacc[0]);
      }
      const int xqk = ki ? xq1 : xq0;
#pragma unroll
      for (int ni = 0; ni < 4; ni++) {
        v8bf vb = *(const v8bf*)&Vs[(ni * 16 + l15) * 64 + xqk];
        o[1][ni] = MFMA16(pahi, vb, o[1][ni]);
        if (doLo) o[0][ni] = MFMA16(palo, vb, o[0][ni]);
      }
    }
  }

  // epilogue: normalize and store both tiles (C-layout rows = quad*4+r)
#pragma unroll
  for (int tl = 0; tl < 2; tl++) {
    const int q0 = tl ? q0hi : q0lo;
    const int row_base = q0 + w * 16 + quad * 4;
    float invl[4];
#pragma unroll
    for (int r = 0; r < 4; r++) invl[r] = 1.0f / lacc[tl][r];
#pragma unroll
    for (int ni = 0; ni < 4; ni++)
#pragma unroll
      for (int r = 0; r < 4; r++) {
        const int tr = b_ * SEQ + row_base + r;
        ATTN[(size_t)tr * HDIM + h * HS + ni * 16 + l15] = f2bf(o[tl][ni][r] * invl[r]);
      }
  }
}

// ---------------- GEMM2: out(4096x1024) = ATTN @ WOT^T, fp32 out ----------------
// 128x64 tiles -> 512 blocks (2/CU); 3-deep counted-vmcnt pipeline (neutral vs
// R0's simple loop per R4 totals; kept unchanged for attribution).
__global__ __launch_bounds__(256) void gemm_out_kernel(
    const unsigned short* __restrict__ Ab, const unsigned short* __restrict__ Wt,
    float* __restrict__ out) {
  __shared__ unsigned short As[3][128 * 32];
  __shared__ unsigned short Bs[3][64 * 32];
  const int m0 = blockIdx.x * 128;
  const int n0 = blockIdx.y * 64;
  const int t = threadIdx.x;
  const int lane = t & 63, w = t >> 6;
  const int wm = w * 32;
  const int quad = lane >> 4, l15 = lane & 15;

  v4f acc[2][4] = {};

  const int rowA = t >> 2;
  const int colA = (t & 3) * 8;
  const unsigned short* gA = Ab + (size_t)(m0 + rowA) * HDIM + colA;
  const unsigned short* gB = Wt + (size_t)(n0 + rowA) * HDIM + colA;

  auto issue = [&](int k0, int buf) {
    async16(gA + k0, &As[buf][t * 8]);
    async16(gA + 64 * HDIM + k0, &As[buf][2048 + t * 8]);
    async16(gB + k0, &Bs[buf][t * 8]);   // rowA is always <64: all threads load B
  };
  auto compute = [&](int buf) {
    v8bf a[2], b[4];
#pragma unroll
    for (int i = 0; i < 2; i++)
      a[i] = *(const v8bf*)&As[buf][(wm + i * 16 + l15) * 32 + quad * 8];
#pragma unroll
    for (int j = 0; j < 4; j++)
      b[j] = *(const v8bf*)&Bs[buf][(j * 16 + l15) * 32 + quad * 8];
#pragma unroll
    for (int i = 0; i < 2; i++)
#pragma unroll
      for (int j = 0; j < 4; j++)
        acc[i][j] = MFMA16(a[i], b[j], acc[i][j]);
  };

  issue(0, 0);
  issue(32, 1);
  asm volatile("s_waitcnt vmcnt(3)" ::: "memory");
  __builtin_amdgcn_s_barrier();
  asm volatile("" ::: "memory");

  int cur = 0;
#pragma unroll 3
  for (int kt = 0; kt < 30; ++kt) {
    int ib = cur + 2; if (ib >= 3) ib -= 3;
    issue((kt + 2) * 32, ib);
    compute(cur);
    asm volatile("s_waitcnt vmcnt(3)" ::: "memory");
    __builtin_amdgcn_s_barrier();
    asm volatile("" ::: "memory");
    if (++cur == 3) cur = 0;
  }
  compute(cur);
  asm volatile("s_waitcnt vmcnt(0)" ::: "memory");
  __builtin_amdgcn_s_barrier();
  asm volatile("" ::: "memory");
  if (++cur == 3) cur = 0;
  compute(cur);

#pragma unroll
  for (int i = 0; i < 2; i++) {
#pragma unroll
    for (int j = 0; j < 4; j++) {
#pragma unroll
      for (int r = 0; r < 4; r++) {
        const int tr = m0 + wm + i * 16 + quad * 4 + r;
        const int c = n0 + j * 16 + l15;
        out[(size_t)tr * HDIM + c] = acc[i][j][r];
      }
    }
  }
}

extern "C" void kernel_launch(void* const* d_in, const int* in_sizes, int n_in,
                              void* d_out, int out_size, void* d_ws, size_t ws_size,
                              hipStream_t stream) {
  (void)in_sizes; (void)n_in; (void)out_size; (void)ws_size;
  const float* x    = (const float*)d_in[0];
  const float* pos  = (const float*)d_in[1];
  const float* Wqkv = (const float*)d_in[2];
  const float* Wout = (const float*)d_in[3];
  float* out = (float*)d_out;

  char* ws = (char*)d_ws;
  unsigned short* XP   = (unsigned short*)(ws);
  unsigned short* X    = (unsigned short*)(ws + ((size_t)8  << 20));
  unsigned short* WQT  = (unsigned short*)(ws + ((size_t)16 << 20));
  unsigned short* WOT  = (unsigned short*)(ws + ((size_t)22 << 20));
  unsigned short* Qb   = (unsigned short*)(ws + ((size_t)24 << 20));
  unsigned short* Kb   = (unsigned short*)(ws + ((size_t)32 << 20));
  unsigned short* VTb  = (unsigned short*)(ws + ((size_t)40 << 20));
  unsigned short* ATTN = (unsigned short*)(ws + ((size_t)48 << 20));

  prep_all_kernel<<<8192, 256, 0, stream>>>(x, pos, Wqkv, Wout, X, XP, WQT, WOT);

  dim3 g1(TOKENS / 128, 3 * HDIM / 128);
  gemm_qkv_kernel<<<g1, 256, 0, stream>>>(XP, X, WQT, Qb, Kb, VTb);

  dim3 g2(2 * NHEADS, 16);
  attn_pair_kernel<<<g2, 256, 0, stream>>>(Qb, Kb, VTb, ATTN);

  dim3 g3(TOKENS / 128, HDIM / 64);
  gemm_out_kernel<<<g3, 256, 0, stream>>>(ATTN, WOT, out);
}

// Round 8
// 181.588 us; speedup vs baseline: 1.7090x; 1.0008x over previous
//
#include <hip/hip_runtime.h>

#define SEQ     2048
#define HDIM    1024
#define TOKENS  4096   // B*SEQ
#define NHEADS  16
#define HS      64
#define LP      72     // padded LDS row stride for Q/P region only

typedef __bf16 v8bf __attribute__((ext_vector_type(8)));
typedef float  v4f  __attribute__((ext_vector_type(4)));

#define MFMA16(a, b, c) __builtin_amdgcn_mfma_f32_16x16x32_bf16((a), (b), (c), 0, 0, 0)

// scores arrive in log2 units: 1/sqrt(64) * log2(e) folded into Q pre-scale
#define QSCALE (0.125f * 1.44269504088896f)

__device__ __forceinline__ unsigned short f2bf(float f) {
  unsigned int u = __float_as_uint(f);
  u += 0x7FFFu + ((u >> 16) & 1u);   // RNE
  return (unsigned short)(u >> 16);
}

__device__ __forceinline__ void async16(const void* g, void* l) {
  __builtin_amdgcn_global_load_lds(
      (const __attribute__((address_space(1))) void*)g,
      (__attribute__((address_space(3))) void*)l, 16, 0, 0);
}

// ---------------- fused prep: x casts + both weight transposes ----------------
__global__ __launch_bounds__(256) void prep_all_kernel(
    const float* __restrict__ x, const float* __restrict__ pos,
    const float* __restrict__ Wqkv, const float* __restrict__ Wout,
    unsigned short* __restrict__ X, unsigned short* __restrict__ XP,
    unsigned short* __restrict__ WQT, unsigned short* __restrict__ WOT) {
  __shared__ float tile[32][33];
  const int id = blockIdx.x;
  if (id < 4096) {
    const int i = (id * 256 + threadIdx.x) * 4;
    float4 xv = *(const float4*)(x + i);
    float4 pv = *(const float4*)(pos + (i & (SEQ * HDIM - 1)));
    ushort4 a, b;
    a.x = f2bf(xv.x); a.y = f2bf(xv.y); a.z = f2bf(xv.z); a.w = f2bf(xv.w);
    b.x = f2bf(xv.x + pv.x); b.y = f2bf(xv.y + pv.y);
    b.z = f2bf(xv.z + pv.z); b.w = f2bf(xv.w + pv.w);
    *(ushort4*)(X + i) = a;
    *(ushort4*)(XP + i) = b;
    return;
  }
  const float* in; unsigned short* out; int R, C, bx, by;
  if (id < 7168) {
    const int t2 = id - 4096;
    in = Wqkv; out = WQT; R = HDIM; C = 3 * HDIM;
    bx = (t2 % 96) * 32; by = (t2 / 96) * 32;
  } else {
    const int t3 = id - 7168;
    in = Wout; out = WOT; R = HDIM; C = HDIM;
    bx = (t3 & 31) * 32; by = (t3 >> 5) * 32;
  }
  const int tx = threadIdx.x & 31, ty = threadIdx.x >> 5;  // (32,8)
#pragma unroll
  for (int j = 0; j < 32; j += 8)
    tile[ty + j][tx] = in[(size_t)(by + ty + j) * C + bx + tx];
  __syncthreads();
#pragma unroll
  for (int j = 0; j < 32; j += 8)
    out[(size_t)(bx + ty + j) * R + by + tx] = f2bf(tile[tx][ty + j]);
}

// ---------------- GEMM1: C(4096x3072) = Aeff(4096x1024) @ Wt(3072x1024)^T ----------------
// R0 serial 2-barrier structure + R6 chunk-XOR LDS swizzle (CONFIRMED win).
// Physical 16B-chunk p holds semantic chunk s = p ^ ((p>>3)&7); staging
// pre-permutes the GLOBAL source (m173 pattern); ds_reads apply the same XOR.
// V blocks compute C^T via operand swap so the V^T store is 32B s-runs.
__global__ __launch_bounds__(256) void gemm_qkv_kernel(
    const unsigned short* __restrict__ XP, const unsigned short* __restrict__ X,
    const unsigned short* __restrict__ Wt,
    unsigned short* __restrict__ Qb, unsigned short* __restrict__ Kb,
    unsigned short* __restrict__ VTb) {
  __shared__ unsigned short As[2][128 * 32];
  __shared__ unsigned short Bs[2][128 * 32];
  const int m0 = blockIdx.x * 128;
  const int n0 = blockIdx.y * 128;
  const bool isV = (n0 >= 2 * HDIM);
  const unsigned short* A = isV ? X : XP;
  const int t = threadIdx.x;
  const int lane = t & 63, w = t >> 6;
  const int wm = (w >> 1) * 64, wn = (w & 1) * 64;
  const int quad = lane >> 4, l15 = lane & 15;

  v4f acc[4][4] = {};

  const int s0c = t ^ ((t >> 3) & 7);
  const int rowA = s0c >> 2;          // 0..63
  const int colA = (s0c & 3) * 8;
  const unsigned short* gA = A + (size_t)(m0 + rowA) * HDIM + colA;
  const unsigned short* gB = Wt + (size_t)(n0 + rowA) * HDIM + colA;

  const int baseA = 4 * (wm + l15) + quad;
  const int pA0 = (baseA ^ ((baseA >> 3) & 7)) * 8;   // element offset, +i*512
  const int baseB = 4 * (wn + l15) + quad;
  const int pB0 = (baseB ^ ((baseB >> 3) & 7)) * 8;

  for (int k0 = 0; k0 < HDIM; k0 += 64) {
    __syncthreads();
#pragma unroll
    for (int kh = 0; kh < 2; kh++) {
      async16(gA + k0 + kh * 32, &As[kh][t * 8]);
      async16(gA + 64 * HDIM + k0 + kh * 32, &As[kh][2048 + t * 8]);
      async16(gB + k0 + kh * 32, &Bs[kh][t * 8]);
      async16(gB + 64 * HDIM + k0 + kh * 32, &Bs[kh][2048 + t * 8]);
    }
    __syncthreads();
#pragma unroll
    for (int kh = 0; kh < 2; kh++) {
      v8bf a[4], b[4];
#pragma unroll
      for (int i = 0; i < 4; i++)
        a[i] = *(const v8bf*)&As[kh][pA0 + i * 512];
#pragma unroll
      for (int i = 0; i < 4; i++)
        b[i] = *(const v8bf*)&Bs[kh][pB0 + i * 512];
      if (isV) {
#pragma unroll
        for (int i = 0; i < 4; i++)
#pragma unroll
          for (int j = 0; j < 4; j++)
            acc[i][j] = MFMA16(b[j], a[i], acc[i][j]);   // C^T
      } else {
#pragma unroll
        for (int i = 0; i < 4; i++)
#pragma unroll
          for (int j = 0; j < 4; j++)
            acc[i][j] = MFMA16(a[i], b[j], acc[i][j]);
      }
    }
  }

  const int b_ = m0 >> 11;
  const int s0 = m0 & (SEQ - 1);

  if (isV) {
    // acc[i][j] = C^T: D[row=quad*4+r -> Wt col (d)][col=l15 -> token (s)]
#pragma unroll
    for (int i = 0; i < 4; i++) {
#pragma unroll
      for (int j = 0; j < 4; j++) {
        const int s_ = s0 + wm + i * 16 + l15;
#pragma unroll
        for (int r = 0; r < 4; r++) {
          const int c2 = (n0 - 2 * HDIM) + wn + j * 16 + quad * 4 + r;
          const int h = c2 >> 6, d = c2 & 63;
          VTb[((size_t)(((b_ << 4) | h) * HS + d)) * SEQ + s_] = f2bf(acc[i][j][r]);
        }
      }
    }
  } else {
    // Q/K[(b,h,s), d]: scatter, 16 consecutive lanes form 32B d-runs
    const float scale = (n0 < HDIM) ? QSCALE : 1.0f;
    unsigned short* dst = (n0 < HDIM) ? Qb : Kb;
#pragma unroll
    for (int i = 0; i < 4; i++) {
#pragma unroll
      for (int j = 0; j < 4; j++) {
#pragma unroll
        for (int r = 0; r < 4; r++) {
          const int s_ = s0 + wm + i * 16 + quad * 4 + r;
          const int c2 = (n0 & (HDIM - 1)) + wn + j * 16 + l15;
          const int h = c2 >> 6, d = c2 & 63;
          dst[((size_t)(((b_ << 4) | h) * SEQ + s_)) * HS + d] =
              f2bf(acc[i][j][r] * scale);
        }
      }
    }
  }
}

// ---------------- flash attention, single-tile blocks for occupancy --------
// R8: the R7 pair structure was GRID-CAPPED at 2 blocks/CU (512 blocks, 8
// waves/CU = 25% occ cap) — latency of K/V reg-prefetch + staging barriers
// couldn't be hidden (45% idle, VALU 37 + MFMA 16). Restructure: ONE 64-row
// q-tile per block, grid 32bh x 32q = 1024 blocks; LDS 25.6KB -> up to 6
// blocks/CU; per-wave state halves. Work per block ~ (q+1) chunks, so
// dispatch heavy-first: q = 31 - blockIdx.y (x-fastest launches q=31 first,
// light tiles fill the tail). Ks/Vs keep the R7 chunk-XOR swizzle (conflict
// free); Ps keeps LP=72. Each wave's Ps region = its own Q rows (no cross-
// wave WAR). Cost: no K-frag pair-sharing (+30% LDS reads, proven non-
// critical in R7) and +35% K/V cache re-reads (L2-served, HBM unaffected).
__global__ __launch_bounds__(256, 2) void attn_pair_kernel(
    const unsigned short* __restrict__ Qp, const unsigned short* __restrict__ Kp,
    const unsigned short* __restrict__ Vp, unsigned short* __restrict__ ATTN) {
  __shared__ unsigned short SM[12800];       // 25,600 B
  unsigned short* Ks = SM;                   // [64][64] linear, XOR-swizzled
  unsigned short* Vs = SM + 4096;            // [64][64] linear (V^T: [d][key])
  unsigned short* QPs = SM + 8192;           // 64*LP union: Qs (init) / Ps (loop)

  const int bh = blockIdx.x;                 // 0..31
  const int qt = 31 - blockIdx.y;            // heavy-first
  const int b_ = bh >> 4, h = bh & 15;
  const int q0 = qt * 64;
  const int t = threadIdx.x;
  const int lane = t & 63, w = t >> 6;
  const int quad = lane >> 4, l15 = lane & 15;

  const unsigned short* Qg = Qp + (size_t)bh * SEQ * HS;
  const unsigned short* Kg = Kp + (size_t)bh * SEQ * HS;
  const unsigned short* Vg = Vp + (size_t)bh * HS * SEQ;

  const int sr = t >> 3, scol = (t & 7) * 8;
  // K/V staging dest: physical chunk for semantic chunk t (and t+256)
  const int pst = (t ^ ((t >> 3) & 7)) * 8;
  // K/V fragment read column XORs: c=quad (half 0), c=quad+4 (half 1)
  const int xq0 = (quad ^ (l15 & 7)) * 8;
  const int xq1 = ((quad + 4) ^ (l15 & 7)) * 8;

  // Q staging: 64 rows
  *(uint4*)&QPs[sr * LP + scol] = *(const uint4*)(Qg + (size_t)(q0 + sr) * HS + scol);
  *(uint4*)&QPs[(sr + 32) * LP + scol] =
      *(const uint4*)(Qg + (size_t)(q0 + sr + 32) * HS + scol);
  __syncthreads();

  // Q rows as B-operand fragments [khalf]; each wave reads ONLY its own 16
  // rows, which are also its Ps region => no cross-wave WAR on the overlay.
  v8bf bq[2];
#pragma unroll
  for (int kh = 0; kh < 2; kh++)
    bq[kh] = *(const v8bf*)&QPs[(w * 16 + l15) * LP + kh * 32 + quad * 8];

  unsigned short* Ps_w = QPs + w * 16 * LP;  // 16 rows/wave

  v8bf ones;
#pragma unroll
  for (int j = 0; j < 8; j++) ones[j] = (__bf16)1.0f;

  v4f o[4] = {};
  v4f lacc = {};

  // register prefetch of chunk 0
  uint4 kr0, kr1, vr0, vr1;
  kr0 = *(const uint4*)(Kg + (size_t)sr * HS + scol);
  kr1 = *(const uint4*)(Kg + (size_t)(sr + 32) * HS + scol);
  vr0 = *(const uint4*)(Vg + (size_t)sr * SEQ + scol);
  vr1 = *(const uint4*)(Vg + (size_t)(sr + 32) * SEQ + scol);

  const int qrow = q0 + w * 16 + l15;  // lane's q-row in S^T

  for (int cI = 0; cI <= qt; cI++) {
    const int kc = cI * 64;
    __syncthreads();  // previous chunk's K/V LDS reads done
    *(uint4*)&Ks[pst] = kr0;
    *(uint4*)&Ks[pst + 2048] = kr1;
    *(uint4*)&Vs[pst] = vr0;
    *(uint4*)&Vs[pst + 2048] = vr1;
    if (cI < qt) {  // prefetch next chunk while computing this one
      const int kn = kc + 64;
      kr0 = *(const uint4*)(Kg + (size_t)(kn + sr) * HS + scol);
      kr1 = *(const uint4*)(Kg + (size_t)(kn + sr + 32) * HS + scol);
      vr0 = *(const uint4*)(Vg + (size_t)sr * SEQ + kn + scol);
      vr1 = *(const uint4*)(Vg + (size_t)(sr + 32) * SEQ + kn + scol);
    }
    __syncthreads();

    // K fragments (A-operand)
    v8bf kf0[4], kf1[4];
#pragma unroll
    for (int ni = 0; ni < 4; ni++) {
      kf0[ni] = *(const v8bf*)&Ks[(ni * 16 + l15) * 64 + xq0];
      kf1[ni] = *(const v8bf*)&Ks[(ni * 16 + l15) * 64 + xq1];
    }

    // ---- S^T = K Q^T, D[key=quad*4+r][qrow=l15] ----
    {
      v4f sc[4] = {};
#pragma unroll
      for (int ni = 0; ni < 4; ni++) {
        sc[ni] = MFMA16(kf0[ni], bq[0], sc[ni]);
        sc[ni] = MFMA16(kf1[ni], bq[1], sc[ni]);
      }
      if (cI == qt) {
#pragma unroll
        for (int ni = 0; ni < 4; ni++) {
          const int key = kc + ni * 16 + quad * 4;
#pragma unroll
          for (int r = 0; r < 4; r++)
            if (key + r > qrow) sc[ni][r] = -1e30f;
        }
      }
#pragma unroll
      for (int ni = 0; ni < 4; ni++) {
        const float p0 = exp2f(sc[ni][0]), p1 = exp2f(sc[ni][1]);
        const float p2 = exp2f(sc[ni][2]), p3 = exp2f(sc[ni][3]);
        uint2 pk;
        pk.x = __builtin_amdgcn_perm(__float_as_uint(p1), __float_as_uint(p0), 0x07060302u);
        pk.y = __builtin_amdgcn_perm(__float_as_uint(p3), __float_as_uint(p2), 0x07060302u);
        *(uint2*)&Ps_w[l15 * LP + ni * 16 + quad * 4] = pk;
      }
    }

    // ---- O += P @ V, l += P @ 1 ----
#pragma unroll
    for (int ki = 0; ki < 2; ki++) {
      v8bf pa = *(const v8bf*)&Ps_w[l15 * LP + ki * 32 + quad * 8];
      lacc = MFMA16(pa, ones, lacc);
      const int xqk = ki ? xq1 : xq0;
#pragma unroll
      for (int ni = 0; ni < 4; ni++) {
        v8bf vb = *(const v8bf*)&Vs[(ni * 16 + l15) * 64 + xqk];
        o[ni] = MFMA16(pa, vb, o[ni]);
      }
    }
  }

  // epilogue: normalize and store (C-layout rows = quad*4+r)
  const int row_base = q0 + w * 16 + quad * 4;
  float invl[4];
#pragma unroll
  for (int r = 0; r < 4; r++) invl[r] = 1.0f / lacc[r];
#pragma unroll
  for (int ni = 0; ni < 4; ni++)
#pragma unroll
    for (int r = 0; r < 4; r++) {
      const int tr = b_ * SEQ + row_base + r;
      ATTN[(size_t)tr * HDIM + h * HS + ni * 16 + l15] = f2bf(o[ni][r] * invl[r]);
    }
}

// ---------------- GEMM2: out(4096x1024) = ATTN @ WOT^T, fp32 out ----------------
// 128x64 tiles -> 512 blocks (2/CU); 3-deep counted-vmcnt pipeline (neutral vs
// R0's simple loop per R4 totals; kept unchanged for attribution).
__global__ __launch_bounds__(256) void gemm_out_kernel(
    const unsigned short* __restrict__ Ab, const unsigned short* __restrict__ Wt,
    float* __restrict__ out) {
  __shared__ unsigned short As[3][128 * 32];
  __shared__ unsigned short Bs[3][64 * 32];
  const int m0 = blockIdx.x * 128;
  const int n0 = blockIdx.y * 64;
  const int t = threadIdx.x;
  const int lane = t & 63, w = t >> 6;
  const int wm = w * 32;
  const int quad = lane >> 4, l15 = lane & 15;

  v4f acc[2][4] = {};

  const int rowA = t >> 2;
  const int colA = (t & 3) * 8;
  const unsigned short* gA = Ab + (size_t)(m0 + rowA) * HDIM + colA;
  const unsigned short* gB = Wt + (size_t)(n0 + rowA) * HDIM + colA;

  auto issue = [&](int k0, int buf) {
    async16(gA + k0, &As[buf][t * 8]);
    async16(gA + 64 * HDIM + k0, &As[buf][2048 + t * 8]);
    async16(gB + k0, &Bs[buf][t * 8]);   // rowA is always <64: all threads load B
  };
  auto compute = [&](int buf) {
    v8bf a[2], b[4];
#pragma unroll
    for (int i = 0; i < 2; i++)
      a[i] = *(const v8bf*)&As[buf][(wm + i * 16 + l15) * 32 + quad * 8];
#pragma unroll
    for (int j = 0; j < 4; j++)
      b[j] = *(const v8bf*)&Bs[buf][(j * 16 + l15) * 32 + quad * 8];
#pragma unroll
    for (int i = 0; i < 2; i++)
#pragma unroll
      for (int j = 0; j < 4; j++)
        acc[i][j] = MFMA16(a[i], b[j], acc[i][j]);
  };

  issue(0, 0);
  issue(32, 1);
  asm volatile("s_waitcnt vmcnt(3)" ::: "memory");
  __builtin_amdgcn_s_barrier();
  asm volatile("" ::: "memory");

  int cur = 0;
#pragma unroll 3
  for (int kt = 0; kt < 30; ++kt) {
    int ib = cur + 2; if (ib >= 3) ib -= 3;
    issue((kt + 2) * 32, ib);
    compute(cur);
    asm volatile("s_waitcnt vmcnt(3)" ::: "memory");
    __builtin_amdgcn_s_barrier();
    asm volatile("" ::: "memory");
    if (++cur == 3) cur = 0;
  }
  compute(cur);
  asm volatile("s_waitcnt vmcnt(0)" ::: "memory");
  __builtin_amdgcn_s_barrier();
  asm volatile("" ::: "memory");
  if (++cur == 3) cur = 0;
  compute(cur);

#pragma unroll
  for (int i = 0; i < 2; i++) {
#pragma unroll
    for (int j = 0; j < 4; j++) {
#pragma unroll
      for (int r = 0; r < 4; r++) {
        const int tr = m0 + wm + i * 16 + quad * 4 + r;
        const int c = n0 + j * 16 + l15;
        out[(size_t)tr * HDIM + c] = acc[i][j][r];
      }
    }
  }
}

extern "C" void kernel_launch(void* const* d_in, const int* in_sizes, int n_in,
                              void* d_out, int out_size, void* d_ws, size_t ws_size,
                              hipStream_t stream) {
  (void)in_sizes; (void)n_in; (void)out_size; (void)ws_size;
  const float* x    = (const float*)d_in[0];
  const float* pos  = (const float*)d_in[1];
  const float* Wqkv = (const float*)d_in[2];
  const float* Wout = (const float*)d_in[3];
  float* out = (float*)d_out;

  char* ws = (char*)d_ws;
  unsigned short* XP   = (unsigned short*)(ws);
  unsigned short* X    = (unsigned short*)(ws + ((size_t)8  << 20));
  unsigned short* WQT  = (unsigned short*)(ws + ((size_t)16 << 20));
  unsigned short* WOT  = (unsigned short*)(ws + ((size_t)22 << 20));
  unsigned short* Qb   = (unsigned short*)(ws + ((size_t)24 << 20));
  unsigned short* Kb   = (unsigned short*)(ws + ((size_t)32 << 20));
  unsigned short* VTb  = (unsigned short*)(ws + ((size_t)40 << 20));
  unsigned short* ATTN = (unsigned short*)(ws + ((size_t)48 << 20));

  prep_all_kernel<<<8192, 256, 0, stream>>>(x, pos, Wqkv, Wout, X, XP, WQT, WOT);

  dim3 g1(TOKENS / 128, 3 * HDIM / 128);
  gemm_qkv_kernel<<<g1, 256, 0, stream>>>(XP, X, WQT, Qb, Kb, VTb);

  dim3 g2(2 * NHEADS, 32);
  attn_pair_kernel<<<g2, 256, 0, stream>>>(Qb, Kb, VTb, ATTN);

  dim3 g3(TOKENS / 128, HDIM / 64);
  gemm_out_kernel<<<g3, 256, 0, stream>>>(ATTN, WOT, out);
}

// Round 9
// 178.475 us; speedup vs baseline: 1.7388x; 1.0174x over previous
//
#include <hip/hip_runtime.h>

#define SEQ     2048
#define HDIM    1024
#define TOKENS  4096   // B*SEQ
#define NHEADS  16
#define HS      64
#define LP      72     // padded LDS row stride for Q/P region only

typedef __bf16 v8bf __attribute__((ext_vector_type(8)));
typedef float  v4f  __attribute__((ext_vector_type(4)));

#define MFMA16(a, b, c) __builtin_amdgcn_mfma_f32_16x16x32_bf16((a), (b), (c), 0, 0, 0)

// scores arrive in log2 units: 1/sqrt(64) * log2(e) folded into Q pre-scale
#define QSCALE (0.125f * 1.44269504088896f)

__device__ __forceinline__ unsigned short f2bf(float f) {
  unsigned int u = __float_as_uint(f);
  u += 0x7FFFu + ((u >> 16) & 1u);   // RNE
  return (unsigned short)(u >> 16);
}

__device__ __forceinline__ void async16(const void* g, void* l) {
  __builtin_amdgcn_global_load_lds(
      (const __attribute__((address_space(1))) void*)g,
      (__attribute__((address_space(3))) void*)l, 16, 0, 0);
}

// ---------------- fused prep: x casts + both weight transposes ----------------
__global__ __launch_bounds__(256) void prep_all_kernel(
    const float* __restrict__ x, const float* __restrict__ pos,
    const float* __restrict__ Wqkv, const float* __restrict__ Wout,
    unsigned short* __restrict__ X, unsigned short* __restrict__ XP,
    unsigned short* __restrict__ WQT, unsigned short* __restrict__ WOT) {
  __shared__ float tile[32][33];
  const int id = blockIdx.x;
  if (id < 4096) {
    const int i = (id * 256 + threadIdx.x) * 4;
    float4 xv = *(const float4*)(x + i);
    float4 pv = *(const float4*)(pos + (i & (SEQ * HDIM - 1)));
    ushort4 a, b;
    a.x = f2bf(xv.x); a.y = f2bf(xv.y); a.z = f2bf(xv.z); a.w = f2bf(xv.w);
    b.x = f2bf(xv.x + pv.x); b.y = f2bf(xv.y + pv.y);
    b.z = f2bf(xv.z + pv.z); b.w = f2bf(xv.w + pv.w);
    *(ushort4*)(X + i) = a;
    *(ushort4*)(XP + i) = b;
    return;
  }
  const float* in; unsigned short* out; int R, C, bx, by;
  if (id < 7168) {
    const int t2 = id - 4096;
    in = Wqkv; out = WQT; R = HDIM; C = 3 * HDIM;
    bx = (t2 % 96) * 32; by = (t2 / 96) * 32;
  } else {
    const int t3 = id - 7168;
    in = Wout; out = WOT; R = HDIM; C = HDIM;
    bx = (t3 & 31) * 32; by = (t3 >> 5) * 32;
  }
  const int tx = threadIdx.x & 31, ty = threadIdx.x >> 5;  // (32,8)
#pragma unroll
  for (int j = 0; j < 32; j += 8)
    tile[ty + j][tx] = in[(size_t)(by + ty + j) * C + bx + tx];
  __syncthreads();
#pragma unroll
  for (int j = 0; j < 32; j += 8)
    out[(size_t)(bx + ty + j) * R + by + tx] = f2bf(tile[tx][ty + j]);
}

// ---------------- GEMM1: C(4096x3072) = Aeff(4096x1024) @ Wt(3072x1024)^T ----------------
// R0 serial 2-barrier structure + R6 chunk-XOR LDS swizzle (CONFIRMED:
// SQ_LDS_BANK_CONFLICT 3.15M -> 0, dur 45.7 -> 43.0us = 600 TF, at the
// 2-barrier-128^2 structure ceiling per guide m230). Physical 16B-chunk p
// holds semantic chunk s = p ^ ((p>>3)&7); staging pre-permutes the GLOBAL
// source (m173 pattern); ds_reads apply the same XOR.
// V blocks compute C^T via operand swap so the V^T store is 32B s-runs.
__global__ __launch_bounds__(256) void gemm_qkv_kernel(
    const unsigned short* __restrict__ XP, const unsigned short* __restrict__ X,
    const unsigned short* __restrict__ Wt,
    unsigned short* __restrict__ Qb, unsigned short* __restrict__ Kb,
    unsigned short* __restrict__ VTb) {
  __shared__ unsigned short As[2][128 * 32];
  __shared__ unsigned short Bs[2][128 * 32];
  const int m0 = blockIdx.x * 128;
  const int n0 = blockIdx.y * 128;
  const bool isV = (n0 >= 2 * HDIM);
  const unsigned short* A = isV ? X : XP;
  const int t = threadIdx.x;
  const int lane = t & 63, w = t >> 6;
  const int wm = (w >> 1) * 64, wn = (w & 1) * 64;
  const int quad = lane >> 4, l15 = lane & 15;

  v4f acc[4][4] = {};

  const int s0c = t ^ ((t >> 3) & 7);
  const int rowA = s0c >> 2;          // 0..63
  const int colA = (s0c & 3) * 8;
  const unsigned short* gA = A + (size_t)(m0 + rowA) * HDIM + colA;
  const unsigned short* gB = Wt + (size_t)(n0 + rowA) * HDIM + colA;

  const int baseA = 4 * (wm + l15) + quad;
  const int pA0 = (baseA ^ ((baseA >> 3) & 7)) * 8;   // element offset, +i*512
  const int baseB = 4 * (wn + l15) + quad;
  const int pB0 = (baseB ^ ((baseB >> 3) & 7)) * 8;

  for (int k0 = 0; k0 < HDIM; k0 += 64) {
    __syncthreads();
#pragma unroll
    for (int kh = 0; kh < 2; kh++) {
      async16(gA + k0 + kh * 32, &As[kh][t * 8]);
      async16(gA + 64 * HDIM + k0 + kh * 32, &As[kh][2048 + t * 8]);
      async16(gB + k0 + kh * 32, &Bs[kh][t * 8]);
      async16(gB + 64 * HDIM + k0 + kh * 32, &Bs[kh][2048 + t * 8]);
    }
    __syncthreads();
#pragma unroll
    for (int kh = 0; kh < 2; kh++) {
      v8bf a[4], b[4];
#pragma unroll
      for (int i = 0; i < 4; i++)
        a[i] = *(const v8bf*)&As[kh][pA0 + i * 512];
#pragma unroll
      for (int i = 0; i < 4; i++)
        b[i] = *(const v8bf*)&Bs[kh][pB0 + i * 512];
      if (isV) {
#pragma unroll
        for (int i = 0; i < 4; i++)
#pragma unroll
          for (int j = 0; j < 4; j++)
            acc[i][j] = MFMA16(b[j], a[i], acc[i][j]);   // C^T
      } else {
#pragma unroll
        for (int i = 0; i < 4; i++)
#pragma unroll
          for (int j = 0; j < 4; j++)
            acc[i][j] = MFMA16(a[i], b[j], acc[i][j]);
      }
    }
  }

  const int b_ = m0 >> 11;
  const int s0 = m0 & (SEQ - 1);

  if (isV) {
    // acc[i][j] = C^T: D[row=quad*4+r -> Wt col (d)][col=l15 -> token (s)]
#pragma unroll
    for (int i = 0; i < 4; i++) {
#pragma unroll
      for (int j = 0; j < 4; j++) {
        const int s_ = s0 + wm + i * 16 + l15;
#pragma unroll
        for (int r = 0; r < 4; r++) {
          const int c2 = (n0 - 2 * HDIM) + wn + j * 16 + quad * 4 + r;
          const int h = c2 >> 6, d = c2 & 63;
          VTb[((size_t)(((b_ << 4) | h) * HS + d)) * SEQ + s_] = f2bf(acc[i][j][r]);
        }
      }
    }
  } else {
    // Q/K[(b,h,s), d]: scatter, 16 consecutive lanes form 32B d-runs
    const float scale = (n0 < HDIM) ? QSCALE : 1.0f;
    unsigned short* dst = (n0 < HDIM) ? Qb : Kb;
#pragma unroll
    for (int i = 0; i < 4; i++) {
#pragma unroll
      for (int j = 0; j < 4; j++) {
#pragma unroll
        for (int r = 0; r < 4; r++) {
          const int s_ = s0 + wm + i * 16 + quad * 4 + r;
          const int c2 = (n0 & (HDIM - 1)) + wn + j * 16 + l15;
          const int h = c2 >> 6, d = c2 & 63;
          dst[((size_t)(((b_ << 4) | h) * SEQ + s_)) * HS + d] =
              f2bf(acc[i][j][r] * scale);
        }
      }
    }
  }
}

// ---------------- flash attention, single-tile blocks (R8 structure) --------
// ONE 64-row q-tile per block, grid 32bh x 32q = 1024 blocks (~4 blocks/CU);
// heavy-first dispatch q = 31 - blockIdx.y. Ks/Vs chunk-XOR swizzled (conflict
// free); Ps keeps LP=72; per-wave Ps region = own Q rows (no cross-wave WAR).
// R9: T5 s_setprio(1/0) around both MFMA clusters — attn blocks are
// independent and phase-staggered (m191 regime where setprio pays +4-7%),
// unlike lockstep GEMM (m190 null).
__global__ __launch_bounds__(256, 2) void attn_pair_kernel(
    const unsigned short* __restrict__ Qp, const unsigned short* __restrict__ Kp,
    const unsigned short* __restrict__ Vp, unsigned short* __restrict__ ATTN) {
  __shared__ unsigned short SM[12800];       // 25,600 B
  unsigned short* Ks = SM;                   // [64][64] linear, XOR-swizzled
  unsigned short* Vs = SM + 4096;            // [64][64] linear (V^T: [d][key])
  unsigned short* QPs = SM + 8192;           // 64*LP union: Qs (init) / Ps (loop)

  const int bh = blockIdx.x;                 // 0..31
  const int qt = 31 - blockIdx.y;            // heavy-first
  const int b_ = bh >> 4, h = bh & 15;
  const int q0 = qt * 64;
  const int t = threadIdx.x;
  const int lane = t & 63, w = t >> 6;
  const int quad = lane >> 4, l15 = lane & 15;

  const unsigned short* Qg = Qp + (size_t)bh * SEQ * HS;
  const unsigned short* Kg = Kp + (size_t)bh * SEQ * HS;
  const unsigned short* Vg = Vp + (size_t)bh * HS * SEQ;

  const int sr = t >> 3, scol = (t & 7) * 8;
  const int pst = (t ^ ((t >> 3) & 7)) * 8;
  const int xq0 = (quad ^ (l15 & 7)) * 8;
  const int xq1 = ((quad + 4) ^ (l15 & 7)) * 8;

  // Q staging: 64 rows
  *(uint4*)&QPs[sr * LP + scol] = *(const uint4*)(Qg + (size_t)(q0 + sr) * HS + scol);
  *(uint4*)&QPs[(sr + 32) * LP + scol] =
      *(const uint4*)(Qg + (size_t)(q0 + sr + 32) * HS + scol);
  __syncthreads();

  v8bf bq[2];
#pragma unroll
  for (int kh = 0; kh < 2; kh++)
    bq[kh] = *(const v8bf*)&QPs[(w * 16 + l15) * LP + kh * 32 + quad * 8];

  unsigned short* Ps_w = QPs + w * 16 * LP;  // 16 rows/wave

  v8bf ones;
#pragma unroll
  for (int j = 0; j < 8; j++) ones[j] = (__bf16)1.0f;

  v4f o[4] = {};
  v4f lacc = {};

  // register prefetch of chunk 0
  uint4 kr0, kr1, vr0, vr1;
  kr0 = *(const uint4*)(Kg + (size_t)sr * HS + scol);
  kr1 = *(const uint4*)(Kg + (size_t)(sr + 32) * HS + scol);
  vr0 = *(const uint4*)(Vg + (size_t)sr * SEQ + scol);
  vr1 = *(const uint4*)(Vg + (size_t)(sr + 32) * SEQ + scol);

  const int qrow = q0 + w * 16 + l15;  // lane's q-row in S^T

  for (int cI = 0; cI <= qt; cI++) {
    const int kc = cI * 64;
    __syncthreads();  // previous chunk's K/V LDS reads done
    *(uint4*)&Ks[pst] = kr0;
    *(uint4*)&Ks[pst + 2048] = kr1;
    *(uint4*)&Vs[pst] = vr0;
    *(uint4*)&Vs[pst + 2048] = vr1;
    if (cI < qt) {  // prefetch next chunk while computing this one
      const int kn = kc + 64;
      kr0 = *(const uint4*)(Kg + (size_t)(kn + sr) * HS + scol);
      kr1 = *(const uint4*)(Kg + (size_t)(kn + sr + 32) * HS + scol);
      vr0 = *(const uint4*)(Vg + (size_t)sr * SEQ + kn + scol);
      vr1 = *(const uint4*)(Vg + (size_t)(sr + 32) * SEQ + kn + scol);
    }
    __syncthreads();

    // K fragments (A-operand)
    v8bf kf0[4], kf1[4];
#pragma unroll
    for (int ni = 0; ni < 4; ni++) {
      kf0[ni] = *(const v8bf*)&Ks[(ni * 16 + l15) * 64 + xq0];
      kf1[ni] = *(const v8bf*)&Ks[(ni * 16 + l15) * 64 + xq1];
    }

    // ---- S^T = K Q^T, D[key=quad*4+r][qrow=l15] ----
    {
      v4f sc[4] = {};
      __builtin_amdgcn_s_setprio(1);
#pragma unroll
      for (int ni = 0; ni < 4; ni++) {
        sc[ni] = MFMA16(kf0[ni], bq[0], sc[ni]);
        sc[ni] = MFMA16(kf1[ni], bq[1], sc[ni]);
      }
      __builtin_amdgcn_s_setprio(0);
      if (cI == qt) {
#pragma unroll
        for (int ni = 0; ni < 4; ni++) {
          const int key = kc + ni * 16 + quad * 4;
#pragma unroll
          for (int r = 0; r < 4; r++)
            if (key + r > qrow) sc[ni][r] = -1e30f;
        }
      }
#pragma unroll
      for (int ni = 0; ni < 4; ni++) {
        const float p0 = exp2f(sc[ni][0]), p1 = exp2f(sc[ni][1]);
        const float p2 = exp2f(sc[ni][2]), p3 = exp2f(sc[ni][3]);
        uint2 pk;
        pk.x = __builtin_amdgcn_perm(__float_as_uint(p1), __float_as_uint(p0), 0x07060302u);
        pk.y = __builtin_amdgcn_perm(__float_as_uint(p3), __float_as_uint(p2), 0x07060302u);
        *(uint2*)&Ps_w[l15 * LP + ni * 16 + quad * 4] = pk;
      }
    }

    // ---- O += P @ V, l += P @ 1 ----
    __builtin_amdgcn_s_setprio(1);
#pragma unroll
    for (int ki = 0; ki < 2; ki++) {
      v8bf pa = *(const v8bf*)&Ps_w[l15 * LP + ki * 32 + quad * 8];
      lacc = MFMA16(pa, ones, lacc);
      const int xqk = ki ? xq1 : xq0;
#pragma unroll
      for (int ni = 0; ni < 4; ni++) {
        v8bf vb = *(const v8bf*)&Vs[(ni * 16 + l15) * 64 + xqk];
        o[ni] = MFMA16(pa, vb, o[ni]);
      }
    }
    __builtin_amdgcn_s_setprio(0);
  }

  // epilogue: normalize and store (C-layout rows = quad*4+r)
  const int row_base = q0 + w * 16 + quad * 4;
  float invl[4];
#pragma unroll
  for (int r = 0; r < 4; r++) invl[r] = 1.0f / lacc[r];
#pragma unroll
  for (int ni = 0; ni < 4; ni++)
#pragma unroll
    for (int r = 0; r < 4; r++) {
      const int tr = b_ * SEQ + row_base + r;
      ATTN[(size_t)tr * HDIM + h * HS + ni * 16 + l15] = f2bf(o[ni][r] * invl[r]);
    }
}

// ---------------- GEMM2: out(4096x1024) = ATTN @ WOT^T, fp32 out ----------------
// 128x64 tiles -> 512 blocks (2/CU); 3-deep counted-vmcnt pipeline. R9: the
// SAME chunk-XOR swizzle proven on gemm_qkv (R6/R8: conflicts 3.15M -> 0) —
// identical 64B-row 8-way bank-start collision, identical fix: permuted
// staging source + XOR'd ds_read base; (base+64i)^v = (base^v)+64i since v
// only touches bits 0-2, so +i*512 / +j*512 read strides are unchanged.
__global__ __launch_bounds__(256) void gemm_out_kernel(
    const unsigned short* __restrict__ Ab, const unsigned short* __restrict__ Wt,
    float* __restrict__ out) {
  __shared__ unsigned short As[3][128 * 32];
  __shared__ unsigned short Bs[3][64 * 32];
  const int m0 = blockIdx.x * 128;
  const int n0 = blockIdx.y * 64;
  const int t = threadIdx.x;
  const int lane = t & 63, w = t >> 6;
  const int wm = w * 32;
  const int quad = lane >> 4, l15 = lane & 15;

  v4f acc[2][4] = {};

  // staging source permutation (chunk-XOR involution, as gemm_qkv)
  const int s0c = t ^ ((t >> 3) & 7);
  const int rowA = s0c >> 2;          // 0..63
  const int colA = (s0c & 3) * 8;
  const unsigned short* gA = Ab + (size_t)(m0 + rowA) * HDIM + colA;
  const unsigned short* gB = Wt + (size_t)(n0 + rowA) * HDIM + colA;

  // XOR'd ds_read bases
  const int baseA = 4 * (wm + l15) + quad;
  const int pA0 = (baseA ^ ((baseA >> 3) & 7)) * 8;   // + i*512
  const int baseB = 4 * l15 + quad;
  const int pB0 = (baseB ^ ((baseB >> 3) & 7)) * 8;   // + j*512

  auto issue = [&](int k0, int buf) {
    async16(gA + k0, &As[buf][t * 8]);
    async16(gA + 64 * HDIM + k0, &As[buf][2048 + t * 8]);
    async16(gB + k0, &Bs[buf][t * 8]);   // 64x32 B tile: all 256 threads
  };
  auto compute = [&](int buf) {
    v8bf a[2], b[4];
#pragma unroll
    for (int i = 0; i < 2; i++)
      a[i] = *(const v8bf*)&As[buf][pA0 + i * 512];
#pragma unroll
    for (int j = 0; j < 4; j++)
      b[j] = *(const v8bf*)&Bs[buf][pB0 + j * 512];
#pragma unroll
    for (int i = 0; i < 2; i++)
#pragma unroll
      for (int j = 0; j < 4; j++)
        acc[i][j] = MFMA16(a[i], b[j], acc[i][j]);
  };

  issue(0, 0);
  issue(32, 1);
  asm volatile("s_waitcnt vmcnt(3)" ::: "memory");
  __builtin_amdgcn_s_barrier();
  asm volatile("" ::: "memory");

  int cur = 0;
#pragma unroll 3
  for (int kt = 0; kt < 30; ++kt) {
    int ib = cur + 2; if (ib >= 3) ib -= 3;
    issue((kt + 2) * 32, ib);
    compute(cur);
    asm volatile("s_waitcnt vmcnt(3)" ::: "memory");
    __builtin_amdgcn_s_barrier();
    asm volatile("" ::: "memory");
    if (++cur == 3) cur = 0;
  }
  compute(cur);
  asm volatile("s_waitcnt vmcnt(0)" ::: "memory");
  __builtin_amdgcn_s_barrier();
  asm volatile("" ::: "memory");
  if (++cur == 3) cur = 0;
  compute(cur);

#pragma unroll
  for (int i = 0; i < 2; i++) {
#pragma unroll
    for (int j = 0; j < 4; j++) {
#pragma unroll
      for (int r = 0; r < 4; r++) {
        const int tr = m0 + wm + i * 16 + quad * 4 + r;
        const int c = n0 + j * 16 + l15;
        out[(size_t)tr * HDIM + c] = acc[i][j][r];
      }
    }
  }
}

extern "C" void kernel_launch(void* const* d_in, const int* in_sizes, int n_in,
                              void* d_out, int out_size, void* d_ws, size_t ws_size,
                              hipStream_t stream) {
  (void)in_sizes; (void)n_in; (void)out_size; (void)ws_size;
  const float* x    = (const float*)d_in[0];
  const float* pos  = (const float*)d_in[1];
  const float* Wqkv = (const float*)d_in[2];
  const float* Wout = (const float*)d_in[3];
  float* out = (float*)d_out;

  char* ws = (char*)d_ws;
  unsigned short* XP   = (unsigned short*)(ws);
  unsigned short* X    = (unsigned short*)(ws + ((size_t)8  << 20));
  unsigned short* WQT  = (unsigned short*)(ws + ((size_t)16 << 20));
  unsigned short* WOT  = (unsigned short*)(ws + ((size_t)22 << 20));
  unsigned short* Qb   = (unsigned short*)(ws + ((size_t)24 << 20));
  unsigned short* Kb   = (unsigned short*)(ws + ((size_t)32 << 20));
  unsigned short* VTb  = (unsigned short*)(ws + ((size_t)40 << 20));
  unsigned short* ATTN = (unsigned short*)(ws + ((size_t)48 << 20));

  prep_all_kernel<<<8192, 256, 0, stream>>>(x, pos, Wqkv, Wout, X, XP, WQT, WOT);

  dim3 g1(TOKENS / 128, 3 * HDIM / 128);
  gemm_qkv_kernel<<<g1, 256, 0, stream>>>(XP, X, WQT, Qb, Kb, VTb);

  dim3 g2(2 * NHEADS, 32);
  attn_pair_kernel<<<g2, 256, 0, stream>>>(Qb, Kb, VTb, ATTN);

  dim3 g3(TOKENS / 128, HDIM / 64);
  gemm_out_kernel<<<g3, 256, 0, stream>>>(ATTN, WOT, out);
}

// Round 10
// 178.245 us; speedup vs baseline: 1.7410x; 1.0013x over previous
//
#include <hip/hip_runtime.h>

#define SEQ     2048
#define HDIM    1024
#define TOKENS  4096   // B*SEQ
#define NHEADS  16
#define HS      64
#define LP      72     // padded LDS row stride for Q/P region only

typedef __bf16 v8bf __attribute__((ext_vector_type(8)));
typedef float  v4f  __attribute__((ext_vector_type(4)));

#define MFMA16(a, b, c) __builtin_amdgcn_mfma_f32_16x16x32_bf16((a), (b), (c), 0, 0, 0)

// scores arrive in log2 units: 1/sqrt(64) * log2(e) folded into Q pre-scale
#define QSCALE (0.125f * 1.44269504088896f)

__device__ __forceinline__ unsigned short f2bf(float f) {
  unsigned int u = __float_as_uint(f);
  u += 0x7FFFu + ((u >> 16) & 1u);   // RNE
  return (unsigned short)(u >> 16);
}

__device__ __forceinline__ void async16(const void* g, void* l) {
  __builtin_amdgcn_global_load_lds(
      (const __attribute__((address_space(1))) void*)g,
      (__attribute__((address_space(3))) void*)l, 16, 0, 0);
}

// ---------------- fused prep: x casts + both weight transposes ----------------
__global__ __launch_bounds__(256) void prep_all_kernel(
    const float* __restrict__ x, const float* __restrict__ pos,
    const float* __restrict__ Wqkv, const float* __restrict__ Wout,
    unsigned short* __restrict__ X, unsigned short* __restrict__ XP,
    unsigned short* __restrict__ WQT, unsigned short* __restrict__ WOT) {
  __shared__ float tile[32][33];
  const int id = blockIdx.x;
  if (id < 4096) {
    const int i = (id * 256 + threadIdx.x) * 4;
    float4 xv = *(const float4*)(x + i);
    float4 pv = *(const float4*)(pos + (i & (SEQ * HDIM - 1)));
    ushort4 a, b;
    a.x = f2bf(xv.x); a.y = f2bf(xv.y); a.z = f2bf(xv.z); a.w = f2bf(xv.w);
    b.x = f2bf(xv.x + pv.x); b.y = f2bf(xv.y + pv.y);
    b.z = f2bf(xv.z + pv.z); b.w = f2bf(xv.w + pv.w);
    *(ushort4*)(X + i) = a;
    *(ushort4*)(XP + i) = b;
    return;
  }
  const float* in; unsigned short* out; int R, C, bx, by;
  if (id < 7168) {
    const int t2 = id - 4096;
    in = Wqkv; out = WQT; R = HDIM; C = 3 * HDIM;
    bx = (t2 % 96) * 32; by = (t2 / 96) * 32;
  } else {
    const int t3 = id - 7168;
    in = Wout; out = WOT; R = HDIM; C = HDIM;
    bx = (t3 & 31) * 32; by = (t3 >> 5) * 32;
  }
  const int tx = threadIdx.x & 31, ty = threadIdx.x >> 5;  // (32,8)
#pragma unroll
  for (int j = 0; j < 32; j += 8)
    tile[ty + j][tx] = in[(size_t)(by + ty + j) * C + bx + tx];
  __syncthreads();
#pragma unroll
  for (int j = 0; j < 32; j += 8)
    out[(size_t)(bx + ty + j) * R + by + tx] = f2bf(tile[tx][ty + j]);
}

// ---------------- GEMM1: C(4096x3072) = Aeff(4096x1024) @ Wt(3072x1024)^T ----------------
// R0 serial 2-barrier structure + R6 chunk-XOR LDS swizzle (CONFIRMED:
// SQ_LDS_BANK_CONFLICT 3.15M -> 0, dur 45.7 -> 42.4us = 609 TF, at the
// 2-barrier-128^2 structure ceiling per guide m230). Physical 16B-chunk p
// holds semantic chunk s = p ^ ((p>>3)&7); staging pre-permutes the GLOBAL
// source (m173 pattern); ds_reads apply the same XOR.
// V blocks compute C^T via operand swap so the V^T store is 32B s-runs.
__global__ __launch_bounds__(256) void gemm_qkv_kernel(
    const unsigned short* __restrict__ XP, const unsigned short* __restrict__ X,
    const unsigned short* __restrict__ Wt,
    unsigned short* __restrict__ Qb, unsigned short* __restrict__ Kb,
    unsigned short* __restrict__ VTb) {
  __shared__ unsigned short As[2][128 * 32];
  __shared__ unsigned short Bs[2][128 * 32];
  const int m0 = blockIdx.x * 128;
  const int n0 = blockIdx.y * 128;
  const bool isV = (n0 >= 2 * HDIM);
  const unsigned short* A = isV ? X : XP;
  const int t = threadIdx.x;
  const int lane = t & 63, w = t >> 6;
  const int wm = (w >> 1) * 64, wn = (w & 1) * 64;
  const int quad = lane >> 4, l15 = lane & 15;

  v4f acc[4][4] = {};

  const int s0c = t ^ ((t >> 3) & 7);
  const int rowA = s0c >> 2;          // 0..63
  const int colA = (s0c & 3) * 8;
  const unsigned short* gA = A + (size_t)(m0 + rowA) * HDIM + colA;
  const unsigned short* gB = Wt + (size_t)(n0 + rowA) * HDIM + colA;

  const int baseA = 4 * (wm + l15) + quad;
  const int pA0 = (baseA ^ ((baseA >> 3) & 7)) * 8;   // element offset, +i*512
  const int baseB = 4 * (wn + l15) + quad;
  const int pB0 = (baseB ^ ((baseB >> 3) & 7)) * 8;

  for (int k0 = 0; k0 < HDIM; k0 += 64) {
    __syncthreads();
#pragma unroll
    for (int kh = 0; kh < 2; kh++) {
      async16(gA + k0 + kh * 32, &As[kh][t * 8]);
      async16(gA + 64 * HDIM + k0 + kh * 32, &As[kh][2048 + t * 8]);
      async16(gB + k0 + kh * 32, &Bs[kh][t * 8]);
      async16(gB + 64 * HDIM + k0 + kh * 32, &Bs[kh][2048 + t * 8]);
    }
    __syncthreads();
#pragma unroll
    for (int kh = 0; kh < 2; kh++) {
      v8bf a[4], b[4];
#pragma unroll
      for (int i = 0; i < 4; i++)
        a[i] = *(const v8bf*)&As[kh][pA0 + i * 512];
#pragma unroll
      for (int i = 0; i < 4; i++)
        b[i] = *(const v8bf*)&Bs[kh][pB0 + i * 512];
      if (isV) {
#pragma unroll
        for (int i = 0; i < 4; i++)
#pragma unroll
          for (int j = 0; j < 4; j++)
            acc[i][j] = MFMA16(b[j], a[i], acc[i][j]);   // C^T
      } else {
#pragma unroll
        for (int i = 0; i < 4; i++)
#pragma unroll
          for (int j = 0; j < 4; j++)
            acc[i][j] = MFMA16(a[i], b[j], acc[i][j]);
      }
    }
  }

  const int b_ = m0 >> 11;
  const int s0 = m0 & (SEQ - 1);

  if (isV) {
    // acc[i][j] = C^T: D[row=quad*4+r -> Wt col (d)][col=l15 -> token (s)]
#pragma unroll
    for (int i = 0; i < 4; i++) {
#pragma unroll
      for (int j = 0; j < 4; j++) {
        const int s_ = s0 + wm + i * 16 + l15;
#pragma unroll
        for (int r = 0; r < 4; r++) {
          const int c2 = (n0 - 2 * HDIM) + wn + j * 16 + quad * 4 + r;
          const int h = c2 >> 6, d = c2 & 63;
          VTb[((size_t)(((b_ << 4) | h) * HS + d)) * SEQ + s_] = f2bf(acc[i][j][r]);
        }
      }
    }
  } else {
    // Q/K[(b,h,s), d]: scatter, 16 consecutive lanes form 32B d-runs
    const float scale = (n0 < HDIM) ? QSCALE : 1.0f;
    unsigned short* dst = (n0 < HDIM) ? Qb : Kb;
#pragma unroll
    for (int i = 0; i < 4; i++) {
#pragma unroll
      for (int j = 0; j < 4; j++) {
#pragma unroll
        for (int r = 0; r < 4; r++) {
          const int s_ = s0 + wm + i * 16 + quad * 4 + r;
          const int c2 = (n0 & (HDIM - 1)) + wn + j * 16 + l15;
          const int h = c2 >> 6, d = c2 & 63;
          dst[((size_t)(((b_ << 4) | h) * SEQ + s_)) * HS + d] =
              f2bf(acc[i][j][r] * scale);
        }
      }
    }
  }
}

// ---------------- flash attention, single-tile blocks (R8 structure) --------
// ONE 64-row q-tile per block, grid 32bh x 32q = 1024 blocks (~4 blocks/CU);
// heavy-first dispatch q = 31 - blockIdx.y. Ks/Vs chunk-XOR swizzled (conflict
// free); Ps keeps LP=72; per-wave Ps region = own Q rows (no cross-wave WAR).
// T5 s_setprio(1/0) around both MFMA clusters (R9: part of -3.1us total win).
__global__ __launch_bounds__(256, 2) void attn_pair_kernel(
    const unsigned short* __restrict__ Qp, const unsigned short* __restrict__ Kp,
    const unsigned short* __restrict__ Vp, unsigned short* __restrict__ ATTN) {
  __shared__ unsigned short SM[12800];       // 25,600 B
  unsigned short* Ks = SM;                   // [64][64] linear, XOR-swizzled
  unsigned short* Vs = SM + 4096;            // [64][64] linear (V^T: [d][key])
  unsigned short* QPs = SM + 8192;           // 64*LP union: Qs (init) / Ps (loop)

  const int bh = blockIdx.x;                 // 0..31
  const int qt = 31 - blockIdx.y;            // heavy-first
  const int b_ = bh >> 4, h = bh & 15;
  const int q0 = qt * 64;
  const int t = threadIdx.x;
  const int lane = t & 63, w = t >> 6;
  const int quad = lane >> 4, l15 = lane & 15;

  const unsigned short* Qg = Qp + (size_t)bh * SEQ * HS;
  const unsigned short* Kg = Kp + (size_t)bh * SEQ * HS;
  const unsigned short* Vg = Vp + (size_t)bh * HS * SEQ;

  const int sr = t >> 3, scol = (t & 7) * 8;
  const int pst = (t ^ ((t >> 3) & 7)) * 8;
  const int xq0 = (quad ^ (l15 & 7)) * 8;
  const int xq1 = ((quad + 4) ^ (l15 & 7)) * 8;

  // Q staging: 64 rows
  *(uint4*)&QPs[sr * LP + scol] = *(const uint4*)(Qg + (size_t)(q0 + sr) * HS + scol);
  *(uint4*)&QPs[(sr + 32) * LP + scol] =
      *(const uint4*)(Qg + (size_t)(q0 + sr + 32) * HS + scol);
  __syncthreads();

  v8bf bq[2];
#pragma unroll
  for (int kh = 0; kh < 2; kh++)
    bq[kh] = *(const v8bf*)&QPs[(w * 16 + l15) * LP + kh * 32 + quad * 8];

  unsigned short* Ps_w = QPs + w * 16 * LP;  // 16 rows/wave

  v8bf ones;
#pragma unroll
  for (int j = 0; j < 8; j++) ones[j] = (__bf16)1.0f;

  v4f o[4] = {};
  v4f lacc = {};

  // register prefetch of chunk 0
  uint4 kr0, kr1, vr0, vr1;
  kr0 = *(const uint4*)(Kg + (size_t)sr * HS + scol);
  kr1 = *(const uint4*)(Kg + (size_t)(sr + 32) * HS + scol);
  vr0 = *(const uint4*)(Vg + (size_t)sr * SEQ + scol);
  vr1 = *(const uint4*)(Vg + (size_t)(sr + 32) * SEQ + scol);

  const int qrow = q0 + w * 16 + l15;  // lane's q-row in S^T

  for (int cI = 0; cI <= qt; cI++) {
    const int kc = cI * 64;
    __syncthreads();  // previous chunk's K/V LDS reads done
    *(uint4*)&Ks[pst] = kr0;
    *(uint4*)&Ks[pst + 2048] = kr1;
    *(uint4*)&Vs[pst] = vr0;
    *(uint4*)&Vs[pst + 2048] = vr1;
    if (cI < qt) {  // prefetch next chunk while computing this one
      const int kn = kc + 64;
      kr0 = *(const uint4*)(Kg + (size_t)(kn + sr) * HS + scol);
      kr1 = *(const uint4*)(Kg + (size_t)(kn + sr + 32) * HS + scol);
      vr0 = *(const uint4*)(Vg + (size_t)sr * SEQ + kn + scol);
      vr1 = *(const uint4*)(Vg + (size_t)(sr + 32) * SEQ + kn + scol);
    }
    __syncthreads();

    // K fragments (A-operand)
    v8bf kf0[4], kf1[4];
#pragma unroll
    for (int ni = 0; ni < 4; ni++) {
      kf0[ni] = *(const v8bf*)&Ks[(ni * 16 + l15) * 64 + xq0];
      kf1[ni] = *(const v8bf*)&Ks[(ni * 16 + l15) * 64 + xq1];
    }

    // ---- S^T = K Q^T, D[key=quad*4+r][qrow=l15] ----
    {
      v4f sc[4] = {};
      __builtin_amdgcn_s_setprio(1);
#pragma unroll
      for (int ni = 0; ni < 4; ni++) {
        sc[ni] = MFMA16(kf0[ni], bq[0], sc[ni]);
        sc[ni] = MFMA16(kf1[ni], bq[1], sc[ni]);
      }
      __builtin_amdgcn_s_setprio(0);
      if (cI == qt) {
#pragma unroll
        for (int ni = 0; ni < 4; ni++) {
          const int key = kc + ni * 16 + quad * 4;
#pragma unroll
          for (int r = 0; r < 4; r++)
            if (key + r > qrow) sc[ni][r] = -1e30f;
        }
      }
#pragma unroll
      for (int ni = 0; ni < 4; ni++) {
        const float p0 = exp2f(sc[ni][0]), p1 = exp2f(sc[ni][1]);
        const float p2 = exp2f(sc[ni][2]), p3 = exp2f(sc[ni][3]);
        uint2 pk;
        pk.x = __builtin_amdgcn_perm(__float_as_uint(p1), __float_as_uint(p0), 0x07060302u);
        pk.y = __builtin_amdgcn_perm(__float_as_uint(p3), __float_as_uint(p2), 0x07060302u);
        *(uint2*)&Ps_w[l15 * LP + ni * 16 + quad * 4] = pk;
      }
    }

    // ---- O += P @ V, l += P @ 1 ----
    __builtin_amdgcn_s_setprio(1);
#pragma unroll
    for (int ki = 0; ki < 2; ki++) {
      v8bf pa = *(const v8bf*)&Ps_w[l15 * LP + ki * 32 + quad * 8];
      lacc = MFMA16(pa, ones, lacc);
      const int xqk = ki ? xq1 : xq0;
#pragma unroll
      for (int ni = 0; ni < 4; ni++) {
        v8bf vb = *(const v8bf*)&Vs[(ni * 16 + l15) * 64 + xqk];
        o[ni] = MFMA16(pa, vb, o[ni]);
      }
    }
    __builtin_amdgcn_s_setprio(0);
  }

  // epilogue: normalize and store (C-layout rows = quad*4+r)
  const int row_base = q0 + w * 16 + quad * 4;
  float invl[4];
#pragma unroll
  for (int r = 0; r < 4; r++) invl[r] = 1.0f / lacc[r];
#pragma unroll
  for (int ni = 0; ni < 4; ni++)
#pragma unroll
    for (int r = 0; r < 4; r++) {
      const int tr = b_ * SEQ + row_base + r;
      ATTN[(size_t)tr * HDIM + h * HS + ni * 16 + l15] = f2bf(o[ni][r] * invl[r]);
    }
}

// ---------------- GEMM2: out(4096x1024) = ATTN @ WOT^T, fp32 out ----------------
// R10: rebuilt as a 64x64-tile clone of gemm_qkv's serial BK=64 2-barrier
// structure. Old shape (128x64, BK=32, 3-deep) had only 8 MFMA/barrier and
// 2 blocks/CU (512 blocks) — the most drain-dominated kernel (~215 TF).
// New: grid (64,16)=1024 blocks -> 4 blocks/CU resident (LDS 16KB, ~64 VGPR
// allow 8); 16 MFMA/K-step; inter-block overlap replaces the explicit
// pipeline (the mechanism measured on gemm_qkv/attn). Chunk-XOR swizzle
// carried over verbatim (R6-verified: (base^v)+64i stride preserved).
__global__ __launch_bounds__(256) void gemm_out_kernel(
    const unsigned short* __restrict__ Ab, const unsigned short* __restrict__ Wt,
    float* __restrict__ out) {
  __shared__ unsigned short As[2][64 * 32];
  __shared__ unsigned short Bs[2][64 * 32];
  const int m0 = blockIdx.x * 64;
  const int n0 = blockIdx.y * 64;
  const int t = threadIdx.x;
  const int lane = t & 63, w = t >> 6;
  const int wm = (w >> 1) * 32, wn = (w & 1) * 32;   // wave tile 32x32
  const int quad = lane >> 4, l15 = lane & 15;

  v4f acc[2][2] = {};

  // staging source permutation (chunk-XOR involution, as gemm_qkv)
  const int s0c = t ^ ((t >> 3) & 7);
  const int rowA = s0c >> 2;          // 0..63
  const int colA = (s0c & 3) * 8;
  const unsigned short* gA = Ab + (size_t)(m0 + rowA) * HDIM + colA;
  const unsigned short* gB = Wt + (size_t)(n0 + rowA) * HDIM + colA;

  // XOR'd ds_read bases (+i*512 / +j*512 strides preserved)
  const int baseA = 4 * (wm + l15) + quad;
  const int pA0 = (baseA ^ ((baseA >> 3) & 7)) * 8;
  const int baseB = 4 * (wn + l15) + quad;
  const int pB0 = (baseB ^ ((baseB >> 3) & 7)) * 8;

  for (int k0 = 0; k0 < HDIM; k0 += 64) {
    __syncthreads();
#pragma unroll
    for (int kh = 0; kh < 2; kh++) {
      async16(gA + k0 + kh * 32, &As[kh][t * 8]);
      async16(gB + k0 + kh * 32, &Bs[kh][t * 8]);
    }
    __syncthreads();
#pragma unroll
    for (int kh = 0; kh < 2; kh++) {
      v8bf a[2], b[2];
#pragma unroll
      for (int i = 0; i < 2; i++)
        a[i] = *(const v8bf*)&As[kh][pA0 + i * 512];
#pragma unroll
      for (int j = 0; j < 2; j++)
        b[j] = *(const v8bf*)&Bs[kh][pB0 + j * 512];
#pragma unroll
      for (int i = 0; i < 2; i++)
#pragma unroll
        for (int j = 0; j < 2; j++)
          acc[i][j] = MFMA16(a[i], b[j], acc[i][j]);
    }
  }

#pragma unroll
  for (int i = 0; i < 2; i++) {
#pragma unroll
    for (int j = 0; j < 2; j++) {
#pragma unroll
      for (int r = 0; r < 4; r++) {
        const int tr = m0 + wm + i * 16 + quad * 4 + r;
        const int c = n0 + wn + j * 16 + l15;
        out[(size_t)tr * HDIM + c] = acc[i][j][r];
      }
    }
  }
}

extern "C" void kernel_launch(void* const* d_in, const int* in_sizes, int n_in,
                              void* d_out, int out_size, void* d_ws, size_t ws_size,
                              hipStream_t stream) {
  (void)in_sizes; (void)n_in; (void)out_size; (void)ws_size;
  const float* x    = (const float*)d_in[0];
  const float* pos  = (const float*)d_in[1];
  const float* Wqkv = (const float*)d_in[2];
  const float* Wout = (const float*)d_in[3];
  float* out = (float*)d_out;

  char* ws = (char*)d_ws;
  unsigned short* XP   = (unsigned short*)(ws);
  unsigned short* X    = (unsigned short*)(ws + ((size_t)8  << 20));
  unsigned short* WQT  = (unsigned short*)(ws + ((size_t)16 << 20));
  unsigned short* WOT  = (unsigned short*)(ws + ((size_t)22 << 20));
  unsigned short* Qb   = (unsigned short*)(ws + ((size_t)24 << 20));
  unsigned short* Kb   = (unsigned short*)(ws + ((size_t)32 << 20));
  unsigned short* VTb  = (unsigned short*)(ws + ((size_t)40 << 20));
  unsigned short* ATTN = (unsigned short*)(ws + ((size_t)48 << 20));

  prep_all_kernel<<<8192, 256, 0, stream>>>(x, pos, Wqkv, Wout, X, XP, WQT, WOT);

  dim3 g1(TOKENS / 128, 3 * HDIM / 128);
  gemm_qkv_kernel<<<g1, 256, 0, stream>>>(XP, X, WQT, Qb, Kb, VTb);

  dim3 g2(2 * NHEADS, 32);
  attn_pair_kernel<<<g2, 256, 0, stream>>>(Qb, Kb, VTb, ATTN);

  dim3 g3(TOKENS / 64, HDIM / 64);
  gemm_out_kernel<<<g3, 256, 0, stream>>>(ATTN, WOT, out);
}